// Round 4
// baseline (11429.839 us; speedup 1.0000x reference)
//
#include <hip/hip_runtime.h>

typedef unsigned short u16;
typedef unsigned int   u32;
typedef __attribute__((ext_vector_type(4))) unsigned int au4;
typedef __attribute__((ext_vector_type(4))) float fx4;
typedef __attribute__((ext_vector_type(8))) __bf16 bf16x8;

#define NTHREADS 1024
#define NBLOCKS  256
#define BB       2
#define STEPS    1024
#define TPTS     1025
#define HDIM     64
#define NZ       16
#define WID      128
#define IND      65
#define HN       1024

__device__ __forceinline__ float bf2f(u16 v) { return __uint_as_float(((u32)v) << 16); }
__device__ __forceinline__ u16 f2bf(float f) {
    u32 u = __float_as_uint(f);
    return (u16)((u + 0x7fffu + ((u >> 16) & 1u)) >> 16);
}
__device__ __forceinline__ float lo16(u32 u) { return __uint_as_float(u << 16); }
__device__ __forceinline__ float hi16(u32 u) { return __uint_as_float(u & 0xffff0000u); }
__device__ __forceinline__ u32 pk(float a, float b) {
    return (u32)f2bf(a) | ((u32)f2bf(b) << 16);
}

// AGPR pinning (validated R6-R8)
__device__ __forceinline__ au4 apin(uint4 v) {
    au4 t; t.x = v.x; t.y = v.y; t.z = v.z; t.w = v.w;
    au4 r;
    asm volatile("" : "=a"(r) : "0"(t));
    return r;
}
__device__ __forceinline__ au4 ageta(au4 a) {
    au4 t;
    asm volatile("" : "=a"(t) : "0"(a));
    return t;
}

template <bool IS32>
__device__ __forceinline__ float ldf(const void* p, int i) {
    return IS32 ? ((const float*)p)[i] : bf2f(((const u16*)p)[i]);
}
template <bool IS32>
__device__ __forceinline__ u16 ldbf(const void* p, int i) {
    return IS32 ? f2bf(((const float*)p)[i]) : ((const u16*)p)[i];
}

__device__ __forceinline__ float rcpf(float x) { return __builtin_amdgcn_rcpf(x); }
__device__ __forceinline__ float lipswish(float x) {
    return 0.909f * x * rcpf(1.0f + __expf(-x));   // inf-safe
}
__device__ __forceinline__ float tanh_fast(float x) {
    float e = __expf(2.0f * fabsf(x));
    float t = 1.0f - 2.0f * rcpf(e + 1.0f);
    return copysignf(t, x);
}
__device__ __forceinline__ void split_bf(float v, u16& hi, u16& lo) {
    hi = f2bf(v);
    lo = f2bf(v - bf2f(hi));
}

// R12 structure: R9's 12-phase layout (best) with 16 waves instead of 8.
//  - Each wave owns HALF the weight rows (a0:3, a1:4, ab:16 frags -> 92 AGPR
//    per wave; per-SIMD AGPR total unchanged at 368). Per-phase dependency
//    chains halve (PE: 4 r8-chains; PA/PC: 1 rtl), and 4 waves/SIMD hide
//    each other's ds_read/MFMA latency. Total issue per CU unchanged.
//  - LDS layout identical to R9 (bank-conflict-free, measured 0).
struct __align__(16) SMem {
    // activations as MFMA B operands: bf16 hi + lo residual
    __align__(16) u16 bxh[BB][96],  bxl[BB][96];        // x=[t,y,pad]
    __align__(16) u16 bh1[2][4][144];                   // [mlp][prt*2+smp][j]
    __align__(16) u16 bh2v[4][144];                     // [prt*2+smp][j]
    __align__(16) u16 bh2c[4][144];                     // [prt*2+smp][j]
    __align__(16) u16 vW2F[4][4][64][8];                // drift L2, frag-major
    // raw MFMA outputs, 4 columns (0,1 = samples hi; 2,3 = samples lo)
    __align__(16) float accL0[4][264];
    __align__(16) float accL2v[4][72];
    __align__(16) float accB[4][1032];                  // also hosts L1 raw acc
    __align__(16) float b0s[256], b1s[256], vb2[HDIM], vsc[HDIM];
    __align__(16) float cb2[HN], csc[HN];
    __align__(16) float roW[8][HDIM];
    __align__(16) float rob[8];
    __align__(16) float tsb[1028];
    __align__(16) float yb[BB][HDIM], g0b[BB][HDIM], fdt[BB][HDIM];
    __align__(16) float dwb[BB][NZ];
};

__device__ __forceinline__ bf16x8 bfrag(const u16* p) {
    return __builtin_bit_cast(bf16x8, *(const uint4*)p);
}
__device__ __forceinline__ fx4 mf1(au4 a, bf16x8 b, fx4 acc) {
    bf16x8 af = __builtin_bit_cast(bf16x8, ageta(a));
    return __builtin_amdgcn_mfma_f32_16x16x32_bf16(af, b, acc, 0, 0, 0);
}

template <bool IS32>
__device__ __forceinline__ uint4 load8(const void* src, int row, int stride, int k0, int Klim) {
    u16 e[8];
    #pragma unroll
    for (int j = 0; j < 8; ++j) {
        int k = k0 + j;
        e[j] = (k < Klim) ? ldbf<IS32>(src, row * stride + k) : (u16)0;
    }
    uint4 v;
    v.x = (u32)e[0] | ((u32)e[1] << 16);
    v.y = (u32)e[2] | ((u32)e[3] << 16);
    v.z = (u32)e[4] | ((u32)e[5] << 16);
    v.w = (u32)e[6] | ((u32)e[7] << 16);
    return v;
}

template <bool IS32>
__device__ __forceinline__ void stage_dw(SMem& sm, const uint4& d, int q, float sdt) {
    if (IS32) {
        const float* pf = (const float*)&d;
        int f = q * 4;
        #pragma unroll
        for (int k = 0; k < 4; ++k)
            sm.dwb[(f + k) >> 4][(f + k) & 15] = pf[k] * sdt;
    } else {
        int f = q * 8;
        u32 u0 = d.x, u1 = d.y, u2 = d.z, u3 = d.w;
        sm.dwb[(f    ) >> 4][(f    ) & 15] = lo16(u0) * sdt;
        sm.dwb[(f + 1) >> 4][(f + 1) & 15] = hi16(u0) * sdt;
        sm.dwb[(f + 2) >> 4][(f + 2) & 15] = lo16(u1) * sdt;
        sm.dwb[(f + 3) >> 4][(f + 3) & 15] = hi16(u1) * sdt;
        sm.dwb[(f + 4) >> 4][(f + 4) & 15] = lo16(u2) * sdt;
        sm.dwb[(f + 5) >> 4][(f + 5) & 15] = hi16(u2) * sdt;
        sm.dwb[(f + 6) >> 4][(f + 6) & 15] = lo16(u3) * sdt;
        sm.dwb[(f + 7) >> 4][(f + 7) & 15] = hi16(u3) * sdt;
    }
}

template <bool IS32>
__device__ __forceinline__ void write_out(void* out, size_t idx, const float* v8) {
    if (IS32) {
        float4 o0, o1;
        o0.x = v8[0]; o0.y = v8[1]; o0.z = v8[2]; o0.w = v8[3];
        o1.x = v8[4]; o1.y = v8[5]; o1.z = v8[6]; o1.w = v8[7];
        ((float4*)out)[idx * 2]     = o0;
        ((float4*)out)[idx * 2 + 1] = o1;
    } else {
        uint4 o;
        o.x = pk(v8[0], v8[1]);
        o.y = pk(v8[2], v8[3]);
        o.z = pk(v8[4], v8[5]);
        o.w = pk(v8[6], v8[7]);
        ((uint4*)out)[idx] = o;
    }
}

template <bool IS32>
__device__ __forceinline__ void
sde_run(SMem& sm,
        const void* ts,  const void* z0,  const void* dW,
        const void* iW0, const void* ib0, const void* iW1, const void* ib1,
        const void* iW2, const void* ib2,
        const void* vW0, const void* vb0, const void* vW1, const void* vb1,
        const void* vW2, const void* vb2, const void* vsc,
        const void* cW0, const void* cb0, const void* cW1, const void* cb1,
        const void* cW2, const void* cb2, const void* csc,
        const void* roW, const void* rob, void* out,
        int tid, int bid)
{
    const int lane = tid & 63, wv = tid >> 6;          // wv 0..15
    const int mm = lane & 15, qq = lane >> 4;
    const int nn = mm;                 // B/D column within tile
    const int smp = nn & 1;            // sample this column carries
    const int prt = (nn >> 1) & 1;     // 0 = hi part, 1 = lo part

    // ---- weight A-fragments -> AGPRs (92 u32/thread; half rows per wave) ----
    au4 a0[3];    // stacked [vW0;cW0]: row 16wv+mm, kt 0..2 (K=65 pad 96)
    au4 a1[4];    // waves0-7 vW1, waves8-15 cW1: row 16(wv&7)+mm, kt 0..3
    au4 ab[16];   // cW2: rows 64wv+16r8+mm, r8 0..3, kt 0..3
    {
        int grow = 16 * wv + mm;
        const void* src = (grow < 128) ? vW0 : cW0;
        int r = grow & 127;
        #pragma unroll
        for (int kt = 0; kt < 3; ++kt)
            a0[kt] = apin(load8<IS32>(src, r, IND, 32 * kt + 8 * qq, IND));
    }
    {
        const void* src = (wv < 8) ? vW1 : cW1;
        int r = 16 * (wv & 7) + mm;
        #pragma unroll
        for (int kt = 0; kt < 4; ++kt)
            a1[kt] = apin(load8<IS32>(src, r, WID, 32 * kt + 8 * qq, WID));
    }
    #pragma unroll
    for (int r8 = 0; r8 < 4; ++r8) {
        int r = 64 * wv + 16 * r8 + mm;
        #pragma unroll
        for (int kt = 0; kt < 4; ++kt)
            ab[r8 * 4 + kt] = apin(load8<IS32>(cW2, r, WID, 32 * kt + 8 * qq, WID));
    }

    // ---- LDS staging ----
    for (int slot = tid; slot < 1024; slot += NTHREADS) {
        int rt = slot >> 8, kt = (slot >> 6) & 3, l = slot & 63;
        int m = l & 15, q = l >> 4;
        uint4 v = load8<IS32>(vW2, 16 * rt + m, WID, 32 * kt + 8 * q, WID);
        *(uint4*)&sm.vW2F[rt][kt][l][0] = v;
    }
    if (tid < 256) {
        sm.b0s[tid] = (tid < 128) ? ldf<IS32>(vb0, tid) : ldf<IS32>(cb0, tid - 128);
        sm.b1s[tid] = (tid < 128) ? ldf<IS32>(vb1, tid) : ldf<IS32>(cb1, tid - 128);
    } else if (tid < 320) {
        int i = tid - 256;
        sm.vb2[i] = ldf<IS32>(vb2, i);
        sm.vsc[i] = ldf<IS32>(vsc, i);
    } else if (tid < 328) {
        sm.rob[tid - 320] = ldf<IS32>(rob, tid - 320);
    } else if (tid >= 384 && tid < 448) {
        int b = (tid - 384) >> 5, k = 65 + ((tid - 384) & 31);
        if (k < 96) { sm.bxh[b][k] = 0; sm.bxl[b][k] = 0; }
    }
    for (int i = tid; i < HN; i += NTHREADS) {
        sm.cb2[i] = ldf<IS32>(cb2, i);
        sm.csc[i] = ldf<IS32>(csc, i);
    }
    if (tid < 512) { int d = tid >> 6, i2 = tid & 63; sm.roW[d][i2] = ldf<IS32>(roW, tid); }
    for (int i = tid; i < TPTS; i += NTHREADS) sm.tsb[i] = ldf<IS32>(ts, i);

    uint4 dwpref;
    if (tid >= 128 && tid < 136) {
        int q = tid - 128;
        if (IS32)       dwpref = ((const uint4*)dW)[(size_t)bid * 8 + q];
        else if (q < 4) dwpref = ((const uint4*)dW)[(size_t)bid * 4 + q];
    }
    __syncthreads();

    const float dt  = sm.tsb[1] - sm.tsb[0];
    const float sdt = sqrtf(dt);
    if (tid >= 128 && tid < 136) {
        int q = tid - 128;
        if (IS32 || q < 4) stage_dw<IS32>(sm, dwpref, q, sdt);
    }

    // ---- initial MLP (VALU, once): z0 -> 128 -> 128 -> y0; scratch accB[0..1] ----
    if (tid < 256) {
        int b = tid >> 7, j = tid & 127;
        float acc = ldf<IS32>(ib0, j);
        #pragma unroll
        for (int k = 0; k < 8; ++k)
            acc = fmaf(ldf<IS32>(iW0, j * 8 + k), ldf<IS32>(z0, (bid * BB + b) * 8 + k), acc);
        sm.accB[0][b * 128 + j] = fmaxf(acc, 0.0f);
    }
    __syncthreads();
    if (tid < 256) {
        int b = tid >> 7, j = tid & 127;
        float acc = ldf<IS32>(ib1, j);
        for (int k = 0; k < WID; ++k)
            acc = fmaf(ldf<IS32>(iW1, j * WID + k), sm.accB[0][b * 128 + k], acc);
        sm.accB[1][b * 128 + j] = fmaxf(acc, 0.0f);
    }
    __syncthreads();
    if (tid < 128) {
        int b = tid >> 6, i = tid & 63;
        float y0 = ldf<IS32>(ib2, i);
        for (int k = 0; k < WID; ++k)
            y0 = fmaf(ldf<IS32>(iW2, i * WID + k), sm.accB[1][b * 128 + k], y0);
        sm.yb[b][i] = y0;
        u16 hi, lo; split_bf(y0, hi, lo);
        sm.bxh[b][1 + i] = hi; sm.bxl[b][1 + i] = lo;
        if (i == 0) {
            u16 thi, tlo; split_bf(sm.tsb[0], thi, tlo);
            sm.bxh[b][0] = thi; sm.bxl[b][0] = tlo;
        }
    }
    __syncthreads();

    // ---- main scan: 12 barriers/step, 16-wave row split ----
    for (int s = 0; s < STEPS; ++s) {
        // PA: L0 both MLPs on x (all 16 waves, 1 chain each) -> accL0; dwb (s>0)
        if (s > 0 && tid >= 128 && tid < 136) {
            int q = tid - 128;
            if (IS32 || q < 4) stage_dw<IS32>(sm, dwpref, q, sdt);
        }
        {
            const u16* xs = prt ? &sm.bxl[smp][0] : &sm.bxh[smp][0];
            bf16x8 bx[3];
            #pragma unroll
            for (int kt = 0; kt < 3; ++kt) bx[kt] = bfrag(&xs[32 * kt + 8 * qq]);
            fx4 acc = {0.f, 0.f, 0.f, 0.f};
            #pragma unroll
            for (int kt = 0; kt < 3; ++kt) acc = mf1(a0[kt], bx[kt], acc);
            int rowb = 16 * wv + 4 * qq;
            if (nn < 4) *(fx4*)&sm.accL0[nn][rowb] = acc;
        }
        __syncthreads();
        // PB: act L0 (512 thr): fold hi+lo cols -> bh1
        if (tid < 512) {
            int r = tid >> 1, c = tid & 1;
            float h = lipswish(sm.accL0[c][r] + sm.accL0[c + 2][r] + sm.b0s[r]);
            u16 hi, lo; split_bf(h, hi, lo);
            int mlp = r >> 7, j = r & 127;
            sm.bh1[mlp][c][j]     = hi;
            sm.bh1[mlp][2 + c][j] = lo;
        }
        __syncthreads();
        // PC: L1 MFMA (waves0-7 drift, 8-15 diffusion) -> raw acc (accB scratch)
        {
            int mlp = (wv < 8) ? 0 : 1;
            const u16* hs = &sm.bh1[mlp][prt * 2 + smp][0];
            bf16x8 bf[4];
            #pragma unroll
            for (int kt = 0; kt < 4; ++kt) bf[kt] = bfrag(&hs[32 * kt + 8 * qq]);
            fx4 acc = {0.f, 0.f, 0.f, 0.f};
            #pragma unroll
            for (int kt = 0; kt < 4; ++kt) acc = mf1(a1[kt], bf[kt], acc);
            int rowb = mlp * 128 + 16 * (wv & 7) + 4 * qq;
            if (nn < 4) *(fx4*)&sm.accB[nn][rowb] = acc;
        }
        __syncthreads();
        // PD: act L1 (512 thr) -> bh2v / bh2c
        if (tid < 512) {
            int r = tid >> 1, c = tid & 1;
            float h = lipswish(sm.accB[c][r] + sm.accB[c + 2][r] + sm.b1s[r]);
            u16 hi, lo; split_bf(h, hi, lo);
            if (r < 128) { sm.bh2v[c][r]           = hi; sm.bh2v[2 + c][r]           = lo; }
            else         { sm.bh2c[c][r - 128]     = hi; sm.bh2c[2 + c][r - 128]     = lo; }
        }
        __syncthreads();
        // PE: big MFMA eval1 (all 16 waves, 4 chains) -> accB; drift L2 (waves 0-3)
        {
            const u16* cs2 = &sm.bh2c[prt * 2 + smp][0];
            bf16x8 bc[4];
            #pragma unroll
            for (int kt = 0; kt < 4; ++kt) bc[kt] = bfrag(&cs2[32 * kt + 8 * qq]);
            #pragma unroll
            for (int r8 = 0; r8 < 4; ++r8) {
                fx4 acc = {0.f, 0.f, 0.f, 0.f};
                #pragma unroll
                for (int kt = 0; kt < 4; ++kt) acc = mf1(ab[r8 * 4 + kt], bc[kt], acc);
                int rowb = 64 * wv + 16 * r8 + 4 * qq;
                if (nn < 4) *(fx4*)&sm.accB[nn][rowb] = acc;
            }
            if (wv < 4) {
                const u16* vs2 = &sm.bh2v[prt * 2 + smp][0];
                fx4 acc = {0.f, 0.f, 0.f, 0.f};
                #pragma unroll
                for (int kt = 0; kt < 4; ++kt) {
                    bf16x8 aw = bfrag(&sm.vW2F[wv][kt][lane][0]);
                    acc = __builtin_amdgcn_mfma_f32_16x16x32_bf16(aw, bfrag(&vs2[32 * kt + 8 * qq]), acc, 0, 0, 0);
                }
                int i0 = 16 * wv + 4 * qq;
                if (nn < 4) *(fx4*)&sm.accL2v[nn][i0] = acc;
            }
        }
        __syncthreads();
        // PF: epilogue 1 (512 thr): g0 fold; fdt (tid<128); x' pack
        if (tid < 512) {
            int b = tid >> 8, h = (tid >> 2) & 63, q4 = tid & 3;
            int rb = 16 * h + 4 * q4;
            fx4 aH = *(const fx4*)&sm.accB[b][rb];
            fx4 aL = *(const fx4*)&sm.accB[b + 2][rb];
            float4 cb = *(const float4*)&sm.cb2[rb];
            float4 cs = *(const float4*)&sm.csc[rb];
            float4 dw = *(const float4*)&sm.dwb[b][4 * q4];
            float v;
            v  = tanh_fast(aH.x + aL.x + cb.x) * cs.x * dw.x;
            v  = fmaf(tanh_fast(aH.y + aL.y + cb.y) * cs.y, dw.y, v);
            v  = fmaf(tanh_fast(aH.z + aL.z + cb.z) * cs.z, dw.z, v);
            v  = fmaf(tanh_fast(aH.w + aL.w + cb.w) * cs.w, dw.w, v);
            v += __shfl_xor(v, 1);
            v += __shfl_xor(v, 2);
            if (tid < 128) {
                int b2 = tid >> 6, i = tid & 63;
                sm.fdt[b2][i] = sm.vsc[i] * tanh_fast(sm.accL2v[b2][i] + sm.accL2v[b2 + 2][i] + sm.vb2[i]) * dt;
            }
            if (q4 == 0) {
                sm.g0b[b][h] = v;
                float xp = sm.yb[b][h] + v;
                u16 hi, lo; split_bf(xp, hi, lo);
                sm.bxh[b][1 + h] = hi; sm.bxl[b][1 + h] = lo;
            }
        }
        __syncthreads();
        // PA2: diffusion L0 on x' (waves 8-15) | readout y_s (tid<128) | dW prefetch
        if (wv >= 8) {
            const u16* xs = prt ? &sm.bxl[smp][0] : &sm.bxh[smp][0];
            bf16x8 bx[3];
            #pragma unroll
            for (int kt = 0; kt < 3; ++kt) bx[kt] = bfrag(&xs[32 * kt + 8 * qq]);
            fx4 acc = {0.f, 0.f, 0.f, 0.f};
            #pragma unroll
            for (int kt = 0; kt < 3; ++kt) acc = mf1(a0[kt], bx[kt], acc);
            int rowb = 16 * wv + 4 * qq;               // 128..255
            if (nn < 4) *(fx4*)&sm.accL0[nn][rowb] = acc;
        } else if (tid < 128) {
            int b = tid >> 6, i = tid & 63;
            float y = sm.yb[b][i];
            float acc8[8];
            #pragma unroll
            for (int d = 0; d < 8; ++d) acc8[d] = sm.roW[d][i] * y;
            #pragma unroll
            for (int m = 1; m < 64; m <<= 1) {
                #pragma unroll
                for (int d = 0; d < 8; ++d) acc8[d] += __shfl_xor(acc8[d], m);
            }
            if (i == 0) {
                float v8[8];
                #pragma unroll
                for (int d = 0; d < 8; ++d) v8[d] = acc8[d] + sm.rob[d];
                write_out<IS32>(out, (size_t)(bid * BB + b) * TPTS + s, v8);
            }
        } else if (tid >= 128 && tid < 136 && s + 1 < STEPS) {
            int q = tid - 128;
            if (IS32)       dwpref = ((const uint4*)dW)[(size_t)(s + 1) * 2048 + bid * 8 + q];
            else if (q < 4) dwpref = ((const uint4*)dW)[(size_t)(s + 1) * 1024 + bid * 4 + q];
        }
        __syncthreads();
        // PB2: act diffusion L0 (256 thr)
        if (tid < 256) {
            int r = 128 + (tid >> 1), c = tid & 1;
            float h = lipswish(sm.accL0[c][r] + sm.accL0[c + 2][r] + sm.b0s[r]);
            u16 hi, lo; split_bf(h, hi, lo);
            sm.bh1[1][c][r - 128]     = hi;
            sm.bh1[1][2 + c][r - 128] = lo;
        }
        __syncthreads();
        // PC2: diffusion L1 MFMA (waves 8-15) -> accB scratch
        if (wv >= 8) {
            const u16* hs = &sm.bh1[1][prt * 2 + smp][0];
            bf16x8 bf[4];
            #pragma unroll
            for (int kt = 0; kt < 4; ++kt) bf[kt] = bfrag(&hs[32 * kt + 8 * qq]);
            fx4 acc = {0.f, 0.f, 0.f, 0.f};
            #pragma unroll
            for (int kt = 0; kt < 4; ++kt) acc = mf1(a1[kt], bf[kt], acc);
            int rowb = 128 + 16 * (wv & 7) + 4 * qq;
            if (nn < 4) *(fx4*)&sm.accB[nn][rowb] = acc;
        }
        __syncthreads();
        // PD2: act diffusion L1 (256 thr)
        if (tid < 256) {
            int r = 128 + (tid >> 1), c = tid & 1;
            float h = lipswish(sm.accB[c][r] + sm.accB[c + 2][r] + sm.b1s[r]);
            u16 hi, lo; split_bf(h, hi, lo);
            sm.bh2c[c][r - 128]     = hi;
            sm.bh2c[2 + c][r - 128] = lo;
        }
        __syncthreads();
        // PE2: big MFMA eval2 (all 16 waves, 4 chains) -> accB
        {
            const u16* cs2 = &sm.bh2c[prt * 2 + smp][0];
            bf16x8 bc[4];
            #pragma unroll
            for (int kt = 0; kt < 4; ++kt) bc[kt] = bfrag(&cs2[32 * kt + 8 * qq]);
            #pragma unroll
            for (int r8 = 0; r8 < 4; ++r8) {
                fx4 acc = {0.f, 0.f, 0.f, 0.f};
                #pragma unroll
                for (int kt = 0; kt < 4; ++kt) acc = mf1(ab[r8 * 4 + kt], bc[kt], acc);
                int rowb = 64 * wv + 16 * r8 + 4 * qq;
                if (nn < 4) *(fx4*)&sm.accB[nn][rowb] = acc;
            }
        }
        __syncthreads();
        // PF2: epilogue 2 (512 thr): g1 fold; y1 update + next-x pack + t
        if (tid < 512) {
            int b = tid >> 8, h = (tid >> 2) & 63, q4 = tid & 3;
            int rb = 16 * h + 4 * q4;
            fx4 aH = *(const fx4*)&sm.accB[b][rb];
            fx4 aL = *(const fx4*)&sm.accB[b + 2][rb];
            float4 cb = *(const float4*)&sm.cb2[rb];
            float4 cs = *(const float4*)&sm.csc[rb];
            float4 dw = *(const float4*)&sm.dwb[b][4 * q4];
            float v;
            v  = tanh_fast(aH.x + aL.x + cb.x) * cs.x * dw.x;
            v  = fmaf(tanh_fast(aH.y + aL.y + cb.y) * cs.y, dw.y, v);
            v  = fmaf(tanh_fast(aH.z + aL.z + cb.z) * cs.z, dw.z, v);
            v  = fmaf(tanh_fast(aH.w + aL.w + cb.w) * cs.w, dw.w, v);
            v += __shfl_xor(v, 1);
            v += __shfl_xor(v, 2);
            if (q4 == 0) {
                float y1 = sm.yb[b][h] + sm.fdt[b][h] + 0.5f * (sm.g0b[b][h] + v);
                sm.yb[b][h] = y1;
                u16 hi, lo; split_bf(y1, hi, lo);
                sm.bxh[b][1 + h] = hi; sm.bxl[b][1 + h] = lo;
                if (h == 0) {
                    u16 thi, tlo; split_bf(sm.tsb[s + 1], thi, tlo);
                    sm.bxh[b][0] = thi; sm.bxl[b][0] = tlo;
                }
            }
        }
        __syncthreads();
    }

    // final readout: y_1024
    if (tid < 128) {
        int b = tid >> 6, i = tid & 63;
        float y = sm.yb[b][i];
        float acc8[8];
        #pragma unroll
        for (int d = 0; d < 8; ++d) acc8[d] = sm.roW[d][i] * y;
        #pragma unroll
        for (int m = 1; m < 64; m <<= 1) {
            #pragma unroll
            for (int d = 0; d < 8; ++d) acc8[d] += __shfl_xor(acc8[d], m);
        }
        if (i == 0) {
            float v8[8];
            #pragma unroll
            for (int d = 0; d < 8; ++d) v8[d] = acc8[d] + sm.rob[d];
            write_out<IS32>(out, (size_t)(bid * BB + b) * TPTS + STEPS, v8);
        }
    }
}

__global__ void
__attribute__((amdgpu_flat_work_group_size(NTHREADS, NTHREADS), amdgpu_waves_per_eu(4, 4)))
sde_kernel(const void* __restrict__ ts,  const void* __restrict__ z0,  const void* __restrict__ dW,
           const void* __restrict__ iW0, const void* __restrict__ ib0, const void* __restrict__ iW1,
           const void* __restrict__ ib1, const void* __restrict__ iW2, const void* __restrict__ ib2,
           const void* __restrict__ vW0, const void* __restrict__ vb0, const void* __restrict__ vW1,
           const void* __restrict__ vb1, const void* __restrict__ vW2, const void* __restrict__ vb2,
           const void* __restrict__ vsc, const void* __restrict__ cW0, const void* __restrict__ cb0,
           const void* __restrict__ cW1, const void* __restrict__ cb1, const void* __restrict__ cW2,
           const void* __restrict__ cb2, const void* __restrict__ csc, const void* __restrict__ roW,
           const void* __restrict__ rob, void* __restrict__ out)
{
    __shared__ SMem sm;
    const int tid = threadIdx.x;
    const int bid = blockIdx.x;

    // dtype detection: u16 word #1 of ts (bf16 -> 0x3A80 != 0; fp32 -> 0)
    const bool is32 = (((const u16*)ts)[1] == 0);

    if (is32) {
        sde_run<true>(sm, ts, z0, dW, iW0, ib0, iW1, ib1, iW2, ib2,
                      vW0, vb0, vW1, vb1, vW2, vb2, vsc,
                      cW0, cb0, cW1, cb1, cW2, cb2, csc, roW, rob, out, tid, bid);
    } else {
        sde_run<false>(sm, ts, z0, dW, iW0, ib0, iW1, ib1, iW2, ib2,
                       vW0, vb0, vW1, vb1, vW2, vb2, vsc,
                       cW0, cb0, cW1, cb1, cW2, cb2, csc, roW, rob, out, tid, bid);
    }
}

extern "C" void kernel_launch(void* const* d_in, const int* in_sizes, int n_in,
                              void* d_out, int out_size, void* d_ws, size_t ws_size,
                              hipStream_t stream) {
    (void)in_sizes; (void)n_in; (void)d_ws; (void)ws_size; (void)out_size;
    hipLaunchKernelGGL(sde_kernel, dim3(NBLOCKS), dim3(NTHREADS), 0, stream,
                       d_in[0], d_in[1], d_in[2], d_in[3], d_in[4], d_in[5], d_in[6],
                       d_in[7], d_in[8], d_in[9], d_in[10], d_in[11], d_in[12], d_in[13],
                       d_in[14], d_in[15], d_in[16], d_in[17], d_in[18], d_in[19], d_in[20],
                       d_in[21], d_in[22], d_in[23], d_in[24], d_out);
}

// Round 6
// 6473.852 us; speedup vs baseline: 1.7655x; 1.7655x over previous
//
#include <hip/hip_runtime.h>

typedef unsigned short u16;
typedef unsigned int   u32;
typedef __attribute__((ext_vector_type(4))) unsigned int au4;
typedef __attribute__((ext_vector_type(4))) float fx4;
typedef __attribute__((ext_vector_type(8))) __bf16 bf16x8;

#define NTHREADS 512
#define NBLOCKS  256
#define BB       2
#define STEPS    1024
#define TPTS     1025
#define HDIM     64
#define NZ       16
#define WID      128
#define IND      65
#define HN       1024

__device__ __forceinline__ float bf2f(u16 v) { return __uint_as_float(((u32)v) << 16); }
__device__ __forceinline__ u16 f2bf(float f) {
    u32 u = __float_as_uint(f);
    return (u16)((u + 0x7fffu + ((u >> 16) & 1u)) >> 16);
}
__device__ __forceinline__ float lo16(u32 u) { return __uint_as_float(u << 16); }
__device__ __forceinline__ float hi16(u32 u) { return __uint_as_float(u & 0xffff0000u); }
__device__ __forceinline__ u32 pk(float a, float b) {
    return (u32)f2bf(a) | ((u32)f2bf(b) << 16);
}

// AGPR pinning (validated R6-R8)
__device__ __forceinline__ au4 apin(uint4 v) {
    au4 t; t.x = v.x; t.y = v.y; t.z = v.z; t.w = v.w;
    au4 r;
    asm volatile("" : "=a"(r) : "0"(t));
    return r;
}
__device__ __forceinline__ au4 ageta(au4 a) {
    au4 t;
    asm volatile("" : "=a"(t) : "0"(a));
    return t;
}

template <bool IS32>
__device__ __forceinline__ float ldf(const void* p, int i) {
    return IS32 ? ((const float*)p)[i] : bf2f(((const u16*)p)[i]);
}
template <bool IS32>
__device__ __forceinline__ u16 ldbf(const void* p, int i) {
    return IS32 ? f2bf(((const float*)p)[i]) : ((const u16*)p)[i];
}

__device__ __forceinline__ float rcpf(float x) { return __builtin_amdgcn_rcpf(x); }
__device__ __forceinline__ float lipswish(float x) {
    return 0.909f * x * rcpf(1.0f + __expf(-x));   // inf-safe
}
__device__ __forceinline__ float tanh_fast(float x) {
    float e = __expf(2.0f * fabsf(x));
    float t = 1.0f - 2.0f * rcpf(e + 1.0f);
    return copysignf(t, x);
}
__device__ __forceinline__ void split_bf(float v, u16& hi, u16& lo) {
    hi = f2bf(v);
    lo = f2bf(v - bf2f(hi));
}

// R13 = R1 structure (12 phases, 8 waves, proven best) + two local changes:
//  1. kt-chain split: every MFMA phase accumulates into TWO parallel accs
//     (depth 4->2 / 3->2) folded by one fx4 VALU add. R3's datum: chained
//     MFMA latency ~100cy/link; with 2 waves/SIMD the chains were exposed.
//  2. output ring buffer (obuf, 512B LDS): readout v8 buffered 8 steps,
//     global stores flushed once per 8 steps -> 7/8 of per-step
//     store->vmcnt(0)->barrier drains removed.
//  LDS layout identical to R9 (bank-conflict-free, measured 0) + obuf.
//  (R5 resubmit: R4 bench was an infra failure — container, not kernel.)
struct __align__(16) SMem {
    // activations as MFMA B operands: bf16 hi + lo residual
    __align__(16) u16 bxh[BB][96],  bxl[BB][96];        // x=[t,y,pad]
    __align__(16) u16 bh1[2][4][144];                   // [mlp][prt*2+smp][j]
    __align__(16) u16 bh2v[4][144];                     // [prt*2+smp][j]
    __align__(16) u16 bh2c[4][144];                     // [prt*2+smp][j]
    __align__(16) u16 vW2F[4][4][64][8];                // drift L2, frag-major
    // raw MFMA outputs, 4 columns (0,1 = samples hi; 2,3 = samples lo)
    __align__(16) float accL0[4][264];
    __align__(16) float accL2v[4][72];
    __align__(16) float accB[4][1032];                  // also hosts L1 raw acc
    __align__(16) float b0s[256], b1s[256], vb2[HDIM], vsc[HDIM];
    __align__(16) float cb2[HN], csc[HN];
    __align__(16) float roW[8][HDIM];
    __align__(16) float rob[8];
    __align__(16) float tsb[1028];
    __align__(16) float yb[BB][HDIM], g0b[BB][HDIM], fdt[BB][HDIM];
    __align__(16) float dwb[BB][NZ];
    __align__(16) float obuf[8][BB][8];                 // readout ring (R13)
};

__device__ __forceinline__ bf16x8 bfrag(const u16* p) {
    return __builtin_bit_cast(bf16x8, *(const uint4*)p);
}
__device__ __forceinline__ fx4 mf1(au4 a, bf16x8 b, fx4 acc) {
    bf16x8 af = __builtin_bit_cast(bf16x8, ageta(a));
    return __builtin_amdgcn_mfma_f32_16x16x32_bf16(af, b, acc, 0, 0, 0);
}

template <bool IS32>
__device__ __forceinline__ uint4 load8(const void* src, int row, int stride, int k0, int Klim) {
    u16 e[8];
    #pragma unroll
    for (int j = 0; j < 8; ++j) {
        int k = k0 + j;
        e[j] = (k < Klim) ? ldbf<IS32>(src, row * stride + k) : (u16)0;
    }
    uint4 v;
    v.x = (u32)e[0] | ((u32)e[1] << 16);
    v.y = (u32)e[2] | ((u32)e[3] << 16);
    v.z = (u32)e[4] | ((u32)e[5] << 16);
    v.w = (u32)e[6] | ((u32)e[7] << 16);
    return v;
}

template <bool IS32>
__device__ __forceinline__ void stage_dw(SMem& sm, const uint4& d, int q, float sdt) {
    if (IS32) {
        const float* pf = (const float*)&d;
        int f = q * 4;
        #pragma unroll
        for (int k = 0; k < 4; ++k)
            sm.dwb[(f + k) >> 4][(f + k) & 15] = pf[k] * sdt;
    } else {
        int f = q * 8;
        u32 u0 = d.x, u1 = d.y, u2 = d.z, u3 = d.w;
        sm.dwb[(f    ) >> 4][(f    ) & 15] = lo16(u0) * sdt;
        sm.dwb[(f + 1) >> 4][(f + 1) & 15] = hi16(u0) * sdt;
        sm.dwb[(f + 2) >> 4][(f + 2) & 15] = lo16(u1) * sdt;
        sm.dwb[(f + 3) >> 4][(f + 3) & 15] = hi16(u1) * sdt;
        sm.dwb[(f + 4) >> 4][(f + 4) & 15] = lo16(u2) * sdt;
        sm.dwb[(f + 5) >> 4][(f + 5) & 15] = hi16(u2) * sdt;
        sm.dwb[(f + 6) >> 4][(f + 6) & 15] = lo16(u3) * sdt;
        sm.dwb[(f + 7) >> 4][(f + 7) & 15] = hi16(u3) * sdt;
    }
}

template <bool IS32>
__device__ __forceinline__ void write_out(void* out, size_t idx, const float* v8) {
    if (IS32) {
        float4 o0, o1;
        o0.x = v8[0]; o0.y = v8[1]; o0.z = v8[2]; o0.w = v8[3];
        o1.x = v8[4]; o1.y = v8[5]; o1.z = v8[6]; o1.w = v8[7];
        ((float4*)out)[idx * 2]     = o0;
        ((float4*)out)[idx * 2 + 1] = o1;
    } else {
        uint4 o;
        o.x = pk(v8[0], v8[1]);
        o.y = pk(v8[2], v8[3]);
        o.z = pk(v8[4], v8[5]);
        o.w = pk(v8[6], v8[7]);
        ((uint4*)out)[idx] = o;
    }
}

template <bool IS32>
__device__ __forceinline__ void
sde_run(SMem& sm,
        const void* ts,  const void* z0,  const void* dW,
        const void* iW0, const void* ib0, const void* iW1, const void* ib1,
        const void* iW2, const void* ib2,
        const void* vW0, const void* vb0, const void* vW1, const void* vb1,
        const void* vW2, const void* vb2, const void* vsc,
        const void* cW0, const void* cb0, const void* cW1, const void* cb1,
        const void* cW2, const void* cb2, const void* csc,
        const void* roW, const void* rob, void* out,
        int tid, int bid)
{
    const int lane = tid & 63, wv = tid >> 6;
    const int mm = lane & 15, qq = lane >> 4;
    const int nn = mm;                 // B/D column within tile
    const int smp = nn & 1;            // sample this column carries
    const int prt = (nn >> 1) & 1;     // 0 = hi part, 1 = lo part

    // ---- weight A-fragments -> AGPRs (184 u32/thread) ----
    au4 a0[6];    // stacked [vW0;cW0]: rows 16(2wv+rtl)+mm, kt 0..2 (K=65 pad 96)
    au4 a1[8];    // waves0-3 vW1, waves4-7 cW1: rows 16(2(wv&3)+rtl)+mm, kt 0..3
    au4 ab[32];   // cW2: rows 128wv+16r8+mm, kt 0..3
    #pragma unroll
    for (int rtl = 0; rtl < 2; ++rtl) {
        int grow = 16 * (2 * wv + rtl) + mm;
        const void* src = (grow < 128) ? vW0 : cW0;
        int r = grow & 127;
        #pragma unroll
        for (int kt = 0; kt < 3; ++kt)
            a0[rtl * 3 + kt] = apin(load8<IS32>(src, r, IND, 32 * kt + 8 * qq, IND));
    }
    {
        const void* src = (wv < 4) ? vW1 : cW1;
        int wl = wv & 3;
        #pragma unroll
        for (int rtl = 0; rtl < 2; ++rtl) {
            int r = 16 * (2 * wl + rtl) + mm;
            #pragma unroll
            for (int kt = 0; kt < 4; ++kt)
                a1[rtl * 4 + kt] = apin(load8<IS32>(src, r, WID, 32 * kt + 8 * qq, WID));
        }
    }
    #pragma unroll
    for (int r8 = 0; r8 < 8; ++r8) {
        int r = 128 * wv + 16 * r8 + mm;
        #pragma unroll
        for (int kt = 0; kt < 4; ++kt)
            ab[r8 * 4 + kt] = apin(load8<IS32>(cW2, r, WID, 32 * kt + 8 * qq, WID));
    }

    // ---- LDS staging ----
    for (int slot = tid; slot < 1024; slot += NTHREADS) {
        int rt = slot >> 8, kt = (slot >> 6) & 3, l = slot & 63;
        int m = l & 15, q = l >> 4;
        uint4 v = load8<IS32>(vW2, 16 * rt + m, WID, 32 * kt + 8 * q, WID);
        *(uint4*)&sm.vW2F[rt][kt][l][0] = v;
    }
    if (tid < 256) {
        sm.b0s[tid] = (tid < 128) ? ldf<IS32>(vb0, tid) : ldf<IS32>(cb0, tid - 128);
        sm.b1s[tid] = (tid < 128) ? ldf<IS32>(vb1, tid) : ldf<IS32>(cb1, tid - 128);
    } else if (tid < 320) {
        int i = tid - 256;
        sm.vb2[i] = ldf<IS32>(vb2, i);
        sm.vsc[i] = ldf<IS32>(vsc, i);
    } else if (tid < 328) {
        sm.rob[tid - 320] = ldf<IS32>(rob, tid - 320);
    } else if (tid >= 384 && tid < 448) {
        int b = (tid - 384) >> 5, k = 65 + ((tid - 384) & 31);
        if (k < 96) { sm.bxh[b][k] = 0; sm.bxl[b][k] = 0; }
    }
    for (int i = tid; i < HN; i += NTHREADS) {
        sm.cb2[i] = ldf<IS32>(cb2, i);
        sm.csc[i] = ldf<IS32>(csc, i);
    }
    { int d = tid >> 6, i2 = tid & 63; sm.roW[d][i2] = ldf<IS32>(roW, tid); }
    for (int i = tid; i < TPTS; i += NTHREADS) sm.tsb[i] = ldf<IS32>(ts, i);

    uint4 dwpref;
    if (tid >= 128 && tid < 136) {
        int q = tid - 128;
        if (IS32)       dwpref = ((const uint4*)dW)[(size_t)bid * 8 + q];
        else if (q < 4) dwpref = ((const uint4*)dW)[(size_t)bid * 4 + q];
    }
    __syncthreads();

    const float dt  = sm.tsb[1] - sm.tsb[0];
    const float sdt = sqrtf(dt);
    if (tid >= 128 && tid < 136) {
        int q = tid - 128;
        if (IS32 || q < 4) stage_dw<IS32>(sm, dwpref, q, sdt);
    }

    // ---- initial MLP (VALU, once): z0 -> 128 -> 128 -> y0; scratch accB[0..1] ----
    if (tid < 256) {
        int b = tid >> 7, j = tid & 127;
        float acc = ldf<IS32>(ib0, j);
        #pragma unroll
        for (int k = 0; k < 8; ++k)
            acc = fmaf(ldf<IS32>(iW0, j * 8 + k), ldf<IS32>(z0, (bid * BB + b) * 8 + k), acc);
        sm.accB[0][b * 128 + j] = fmaxf(acc, 0.0f);
    }
    __syncthreads();
    if (tid < 256) {
        int b = tid >> 7, j = tid & 127;
        float acc = ldf<IS32>(ib1, j);
        for (int k = 0; k < WID; ++k)
            acc = fmaf(ldf<IS32>(iW1, j * WID + k), sm.accB[0][b * 128 + k], acc);
        sm.accB[1][b * 128 + j] = fmaxf(acc, 0.0f);
    }
    __syncthreads();
    if (tid < 128) {
        int b = tid >> 6, i = tid & 63;
        float y0 = ldf<IS32>(ib2, i);
        for (int k = 0; k < WID; ++k)
            y0 = fmaf(ldf<IS32>(iW2, i * WID + k), sm.accB[1][b * 128 + k], y0);
        sm.yb[b][i] = y0;
        u16 hi, lo; split_bf(y0, hi, lo);
        sm.bxh[b][1 + i] = hi; sm.bxl[b][1 + i] = lo;
        if (i == 0) {
            u16 thi, tlo; split_bf(sm.tsb[0], thi, tlo);
            sm.bxh[b][0] = thi; sm.bxl[b][0] = tlo;
        }
    }
    __syncthreads();

    // ---- main scan: 12 barriers/step (R1 structure), kt-split chains ----
    for (int s = 0; s < STEPS; ++s) {
        // PA: L0 both MLPs on x (all waves) -> raw accL0 cols 0-3; stage dwb (s>0)
        if (s > 0 && tid >= 128 && tid < 136) {
            int q = tid - 128;
            if (IS32 || q < 4) stage_dw<IS32>(sm, dwpref, q, sdt);
        }
        {
            const u16* xs = prt ? &sm.bxl[smp][0] : &sm.bxh[smp][0];
            bf16x8 bx[3];
            #pragma unroll
            for (int kt = 0; kt < 3; ++kt) bx[kt] = bfrag(&xs[32 * kt + 8 * qq]);
            #pragma unroll
            for (int rtl = 0; rtl < 2; ++rtl) {
                fx4 acc0 = {0.f, 0.f, 0.f, 0.f};
                fx4 acc1 = {0.f, 0.f, 0.f, 0.f};
                acc0 = mf1(a0[rtl * 3 + 0], bx[0], acc0);
                acc0 = mf1(a0[rtl * 3 + 1], bx[1], acc0);
                acc1 = mf1(a0[rtl * 3 + 2], bx[2], acc1);
                fx4 acc = acc0 + acc1;
                int rowb = 16 * (2 * wv + rtl) + 4 * qq;
                if (nn < 4) *(fx4*)&sm.accL0[nn][rowb] = acc;
            }
        }
        __syncthreads();
        // PB: act L0 (512 thr): fold hi+lo cols -> bh1
        {
            int r = tid >> 1, c = tid & 1;
            float h = lipswish(sm.accL0[c][r] + sm.accL0[c + 2][r] + sm.b0s[r]);
            u16 hi, lo; split_bf(h, hi, lo);
            int mlp = r >> 7, j = r & 127;
            sm.bh1[mlp][c][j]     = hi;
            sm.bh1[mlp][2 + c][j] = lo;
        }
        __syncthreads();
        // PC: L1 MFMA (waves0-3 drift, 4-7 diffusion) -> raw acc (accB scratch)
        {
            int mlp = (wv < 4) ? 0 : 1, wl = wv & 3;
            const u16* hs = &sm.bh1[mlp][prt * 2 + smp][0];
            bf16x8 bf[4];
            #pragma unroll
            for (int kt = 0; kt < 4; ++kt) bf[kt] = bfrag(&hs[32 * kt + 8 * qq]);
            #pragma unroll
            for (int rtl = 0; rtl < 2; ++rtl) {
                fx4 acc0 = {0.f, 0.f, 0.f, 0.f};
                fx4 acc1 = {0.f, 0.f, 0.f, 0.f};
                acc0 = mf1(a1[rtl * 4 + 0], bf[0], acc0);
                acc0 = mf1(a1[rtl * 4 + 1], bf[1], acc0);
                acc1 = mf1(a1[rtl * 4 + 2], bf[2], acc1);
                acc1 = mf1(a1[rtl * 4 + 3], bf[3], acc1);
                fx4 acc = acc0 + acc1;
                int rowb = mlp * 128 + 16 * (2 * wl + rtl) + 4 * qq;
                if (nn < 4) *(fx4*)&sm.accB[nn][rowb] = acc;
            }
        }
        __syncthreads();
        // PD: act L1 (512 thr) -> bh2v / bh2c
        {
            int r = tid >> 1, c = tid & 1;
            float h = lipswish(sm.accB[c][r] + sm.accB[c + 2][r] + sm.b1s[r]);
            u16 hi, lo; split_bf(h, hi, lo);
            if (r < 128) { sm.bh2v[c][r]           = hi; sm.bh2v[2 + c][r]           = lo; }
            else         { sm.bh2c[c][r - 128]     = hi; sm.bh2c[2 + c][r - 128]     = lo; }
        }
        __syncthreads();
        // PE: big MFMA eval1 (all waves) -> accB; drift L2 (waves 0-3) -> accL2v
        {
            const u16* cs2 = &sm.bh2c[prt * 2 + smp][0];
            bf16x8 bc[4];
            #pragma unroll
            for (int kt = 0; kt < 4; ++kt) bc[kt] = bfrag(&cs2[32 * kt + 8 * qq]);
            #pragma unroll
            for (int r8 = 0; r8 < 8; ++r8) {
                fx4 acc0 = {0.f, 0.f, 0.f, 0.f};
                fx4 acc1 = {0.f, 0.f, 0.f, 0.f};
                acc0 = mf1(ab[r8 * 4 + 0], bc[0], acc0);
                acc0 = mf1(ab[r8 * 4 + 1], bc[1], acc0);
                acc1 = mf1(ab[r8 * 4 + 2], bc[2], acc1);
                acc1 = mf1(ab[r8 * 4 + 3], bc[3], acc1);
                fx4 acc = acc0 + acc1;
                int rowb = 128 * wv + 16 * r8 + 4 * qq;
                if (nn < 4) *(fx4*)&sm.accB[nn][rowb] = acc;
            }
            if (wv < 4) {
                const u16* vs2 = &sm.bh2v[prt * 2 + smp][0];
                fx4 acc0 = {0.f, 0.f, 0.f, 0.f};
                fx4 acc1 = {0.f, 0.f, 0.f, 0.f};
                #pragma unroll
                for (int kt = 0; kt < 4; ++kt) {
                    bf16x8 aw = bfrag(&sm.vW2F[wv][kt][lane][0]);
                    if (kt < 2) acc0 = __builtin_amdgcn_mfma_f32_16x16x32_bf16(aw, bfrag(&vs2[32 * kt + 8 * qq]), acc0, 0, 0, 0);
                    else        acc1 = __builtin_amdgcn_mfma_f32_16x16x32_bf16(aw, bfrag(&vs2[32 * kt + 8 * qq]), acc1, 0, 0, 0);
                }
                fx4 acc = acc0 + acc1;
                int i0 = 16 * wv + 4 * qq;
                if (nn < 4) *(fx4*)&sm.accL2v[nn][i0] = acc;
            }
        }
        __syncthreads();
        // PF: epilogue 1 (512 thr): g0 fold; fdt (tid<128); x' pack
        {
            int b = tid >> 8, h = (tid >> 2) & 63, q4 = tid & 3;
            int rb = 16 * h + 4 * q4;
            fx4 aH = *(const fx4*)&sm.accB[b][rb];
            fx4 aL = *(const fx4*)&sm.accB[b + 2][rb];
            float4 cb = *(const float4*)&sm.cb2[rb];
            float4 cs = *(const float4*)&sm.csc[rb];
            float4 dw = *(const float4*)&sm.dwb[b][4 * q4];
            float v;
            v  = tanh_fast(aH.x + aL.x + cb.x) * cs.x * dw.x;
            v  = fmaf(tanh_fast(aH.y + aL.y + cb.y) * cs.y, dw.y, v);
            v  = fmaf(tanh_fast(aH.z + aL.z + cb.z) * cs.z, dw.z, v);
            v  = fmaf(tanh_fast(aH.w + aL.w + cb.w) * cs.w, dw.w, v);
            v += __shfl_xor(v, 1);
            v += __shfl_xor(v, 2);
            if (tid < 128) {
                int b2 = tid >> 6, i = tid & 63;
                sm.fdt[b2][i] = sm.vsc[i] * tanh_fast(sm.accL2v[b2][i] + sm.accL2v[b2 + 2][i] + sm.vb2[i]) * dt;
            }
            if (q4 == 0) {
                sm.g0b[b][h] = v;
                float xp = sm.yb[b][h] + v;
                u16 hi, lo; split_bf(xp, hi, lo);
                sm.bxh[b][1 + h] = hi; sm.bxl[b][1 + h] = lo;
            }
        }
        __syncthreads();
        // PA2: diffusion L0 on x' (waves 4-7) | readout y_s (tid<128, ring-buffered)
        //      | dW prefetch
        if (wv >= 4) {
            const u16* xs = prt ? &sm.bxl[smp][0] : &sm.bxh[smp][0];
            bf16x8 bx[3];
            #pragma unroll
            for (int kt = 0; kt < 3; ++kt) bx[kt] = bfrag(&xs[32 * kt + 8 * qq]);
            #pragma unroll
            for (int rtl = 0; rtl < 2; ++rtl) {
                fx4 acc0 = {0.f, 0.f, 0.f, 0.f};
                fx4 acc1 = {0.f, 0.f, 0.f, 0.f};
                acc0 = mf1(a0[rtl * 3 + 0], bx[0], acc0);
                acc0 = mf1(a0[rtl * 3 + 1], bx[1], acc0);
                acc1 = mf1(a0[rtl * 3 + 2], bx[2], acc1);
                fx4 acc = acc0 + acc1;
                int rowb = 16 * (2 * wv + rtl) + 4 * qq;   // 128..255
                if (nn < 4) *(fx4*)&sm.accL0[nn][rowb] = acc;
            }
        } else if (tid < 128) {
            int b = tid >> 6, i = tid & 63;
            float y = sm.yb[b][i];
            float acc8[8];
            #pragma unroll
            for (int d = 0; d < 8; ++d) acc8[d] = sm.roW[d][i] * y;
            #pragma unroll
            for (int m = 1; m < 64; m <<= 1) {
                #pragma unroll
                for (int d = 0; d < 8; ++d) acc8[d] += __shfl_xor(acc8[d], m);
            }
            if (i == 0) {
                #pragma unroll
                for (int d = 0; d < 8; ++d) sm.obuf[s & 7][b][d] = acc8[d] + sm.rob[d];
                if ((s & 7) == 7) {
                    // flush 8 buffered steps (same thread wrote them; no sync)
                    #pragma unroll
                    for (int k = 0; k < 8; ++k) {
                        float v8[8];
                        #pragma unroll
                        for (int d = 0; d < 8; ++d) v8[d] = sm.obuf[k][b][d];
                        write_out<IS32>(out, (size_t)(bid * BB + b) * TPTS + (s - 7 + k), v8);
                    }
                }
            }
        } else if (tid >= 128 && tid < 136 && s + 1 < STEPS) {
            int q = tid - 128;
            if (IS32)       dwpref = ((const uint4*)dW)[(size_t)(s + 1) * 2048 + bid * 8 + q];
            else if (q < 4) dwpref = ((const uint4*)dW)[(size_t)(s + 1) * 1024 + bid * 4 + q];
        }
        __syncthreads();
        // PB2: act diffusion L0 (256 thr)
        if (tid < 256) {
            int r = 128 + (tid >> 1), c = tid & 1;
            float h = lipswish(sm.accL0[c][r] + sm.accL0[c + 2][r] + sm.b0s[r]);
            u16 hi, lo; split_bf(h, hi, lo);
            sm.bh1[1][c][r - 128]     = hi;
            sm.bh1[1][2 + c][r - 128] = lo;
        }
        __syncthreads();
        // PC2: diffusion L1 MFMA (waves 4-7) -> accB scratch
        if (wv >= 4) {
            int wl = wv & 3;
            const u16* hs = &sm.bh1[1][prt * 2 + smp][0];
            bf16x8 bf[4];
            #pragma unroll
            for (int kt = 0; kt < 4; ++kt) bf[kt] = bfrag(&hs[32 * kt + 8 * qq]);
            #pragma unroll
            for (int rtl = 0; rtl < 2; ++rtl) {
                fx4 acc0 = {0.f, 0.f, 0.f, 0.f};
                fx4 acc1 = {0.f, 0.f, 0.f, 0.f};
                acc0 = mf1(a1[rtl * 4 + 0], bf[0], acc0);
                acc0 = mf1(a1[rtl * 4 + 1], bf[1], acc0);
                acc1 = mf1(a1[rtl * 4 + 2], bf[2], acc1);
                acc1 = mf1(a1[rtl * 4 + 3], bf[3], acc1);
                fx4 acc = acc0 + acc1;
                int rowb = 128 + 16 * (2 * wl + rtl) + 4 * qq;
                if (nn < 4) *(fx4*)&sm.accB[nn][rowb] = acc;
            }
        }
        __syncthreads();
        // PD2: act diffusion L1 (256 thr)
        if (tid < 256) {
            int r = 128 + (tid >> 1), c = tid & 1;
            float h = lipswish(sm.accB[c][r] + sm.accB[c + 2][r] + sm.b1s[r]);
            u16 hi, lo; split_bf(h, hi, lo);
            sm.bh2c[c][r - 128]     = hi;
            sm.bh2c[2 + c][r - 128] = lo;
        }
        __syncthreads();
        // PE2: big MFMA eval2 (all waves) -> accB
        {
            const u16* cs2 = &sm.bh2c[prt * 2 + smp][0];
            bf16x8 bc[4];
            #pragma unroll
            for (int kt = 0; kt < 4; ++kt) bc[kt] = bfrag(&cs2[32 * kt + 8 * qq]);
            #pragma unroll
            for (int r8 = 0; r8 < 8; ++r8) {
                fx4 acc0 = {0.f, 0.f, 0.f, 0.f};
                fx4 acc1 = {0.f, 0.f, 0.f, 0.f};
                acc0 = mf1(ab[r8 * 4 + 0], bc[0], acc0);
                acc0 = mf1(ab[r8 * 4 + 1], bc[1], acc0);
                acc1 = mf1(ab[r8 * 4 + 2], bc[2], acc1);
                acc1 = mf1(ab[r8 * 4 + 3], bc[3], acc1);
                fx4 acc = acc0 + acc1;
                int rowb = 128 * wv + 16 * r8 + 4 * qq;
                if (nn < 4) *(fx4*)&sm.accB[nn][rowb] = acc;
            }
        }
        __syncthreads();
        // PF2: epilogue 2 (512 thr): g1 fold; y1 update + next-x pack + t
        {
            int b = tid >> 8, h = (tid >> 2) & 63, q4 = tid & 3;
            int rb = 16 * h + 4 * q4;
            fx4 aH = *(const fx4*)&sm.accB[b][rb];
            fx4 aL = *(const fx4*)&sm.accB[b + 2][rb];
            float4 cb = *(const float4*)&sm.cb2[rb];
            float4 cs = *(const float4*)&sm.csc[rb];
            float4 dw = *(const float4*)&sm.dwb[b][4 * q4];
            float v;
            v  = tanh_fast(aH.x + aL.x + cb.x) * cs.x * dw.x;
            v  = fmaf(tanh_fast(aH.y + aL.y + cb.y) * cs.y, dw.y, v);
            v  = fmaf(tanh_fast(aH.z + aL.z + cb.z) * cs.z, dw.z, v);
            v  = fmaf(tanh_fast(aH.w + aL.w + cb.w) * cs.w, dw.w, v);
            v += __shfl_xor(v, 1);
            v += __shfl_xor(v, 2);
            if (q4 == 0) {
                float y1 = sm.yb[b][h] + sm.fdt[b][h] + 0.5f * (sm.g0b[b][h] + v);
                sm.yb[b][h] = y1;
                u16 hi, lo; split_bf(y1, hi, lo);
                sm.bxh[b][1 + h] = hi; sm.bxl[b][1 + h] = lo;
                if (h == 0) {
                    u16 thi, tlo; split_bf(sm.tsb[s + 1], thi, tlo);
                    sm.bxh[b][0] = thi; sm.bxl[b][0] = tlo;
                }
            }
        }
        __syncthreads();
    }

    // final readout: y_1024
    if (tid < 128) {
        int b = tid >> 6, i = tid & 63;
        float y = sm.yb[b][i];
        float acc8[8];
        #pragma unroll
        for (int d = 0; d < 8; ++d) acc8[d] = sm.roW[d][i] * y;
        #pragma unroll
        for (int m = 1; m < 64; m <<= 1) {
            #pragma unroll
            for (int d = 0; d < 8; ++d) acc8[d] += __shfl_xor(acc8[d], m);
        }
        if (i == 0) {
            float v8[8];
            #pragma unroll
            for (int d = 0; d < 8; ++d) v8[d] = acc8[d] + sm.rob[d];
            write_out<IS32>(out, (size_t)(bid * BB + b) * TPTS + STEPS, v8);
        }
    }
}

__global__ void
__attribute__((amdgpu_flat_work_group_size(NTHREADS, NTHREADS), amdgpu_waves_per_eu(2, 2)))
sde_kernel(const void* __restrict__ ts,  const void* __restrict__ z0,  const void* __restrict__ dW,
           const void* __restrict__ iW0, const void* __restrict__ ib0, const void* __restrict__ iW1,
           const void* __restrict__ ib1, const void* __restrict__ iW2, const void* __restrict__ ib2,
           const void* __restrict__ vW0, const void* __restrict__ vb0, const void* __restrict__ vW1,
           const void* __restrict__ vb1, const void* __restrict__ vW2, const void* __restrict__ vb2,
           const void* __restrict__ vsc, const void* __restrict__ cW0, const void* __restrict__ cb0,
           const void* __restrict__ cW1, const void* __restrict__ cb1, const void* __restrict__ cW2,
           const void* __restrict__ cb2, const void* __restrict__ csc, const void* __restrict__ roW,
           const void* __restrict__ rob, void* __restrict__ out)
{
    __shared__ SMem sm;
    const int tid = threadIdx.x;
    const int bid = blockIdx.x;

    // dtype detection: u16 word #1 of ts (bf16 -> 0x3A80 != 0; fp32 -> 0)
    const bool is32 = (((const u16*)ts)[1] == 0);

    if (is32) {
        sde_run<true>(sm, ts, z0, dW, iW0, ib0, iW1, ib1, iW2, ib2,
                      vW0, vb0, vW1, vb1, vW2, vb2, vsc,
                      cW0, cb0, cW1, cb1, cW2, cb2, csc, roW, rob, out, tid, bid);
    } else {
        sde_run<false>(sm, ts, z0, dW, iW0, ib0, iW1, ib1, iW2, ib2,
                       vW0, vb0, vW1, vb1, vW2, vb2, vsc,
                       cW0, cb0, cW1, cb1, cW2, cb2, csc, roW, rob, out, tid, bid);
    }
}

extern "C" void kernel_launch(void* const* d_in, const int* in_sizes, int n_in,
                              void* d_out, int out_size, void* d_ws, size_t ws_size,
                              hipStream_t stream) {
    (void)in_sizes; (void)n_in; (void)d_ws; (void)ws_size; (void)out_size;
    hipLaunchKernelGGL(sde_kernel, dim3(NBLOCKS), dim3(NTHREADS), 0, stream,
                       d_in[0], d_in[1], d_in[2], d_in[3], d_in[4], d_in[5], d_in[6],
                       d_in[7], d_in[8], d_in[9], d_in[10], d_in[11], d_in[12], d_in[13],
                       d_in[14], d_in[15], d_in[16], d_in[17], d_in[18], d_in[19], d_in[20],
                       d_in[21], d_in[22], d_in[23], d_in[24], d_out);
}

// Round 7
// 5457.204 us; speedup vs baseline: 2.0944x; 1.1863x over previous
//
#include <hip/hip_runtime.h>

typedef unsigned short u16;
typedef unsigned int   u32;
typedef __attribute__((ext_vector_type(4))) unsigned int au4;
typedef __attribute__((ext_vector_type(4))) float fx4;
typedef __attribute__((ext_vector_type(8))) __bf16 bf16x8;

#define NTHREADS 512
#define NBLOCKS  256
#define BB       2
#define STEPS    1024
#define TPTS     1025
#define HDIM     64
#define NZ       16
#define WID      128
#define IND      65
#define HN       1024

__device__ __forceinline__ float bf2f(u16 v) { return __uint_as_float(((u32)v) << 16); }
__device__ __forceinline__ u16 f2bf(float f) {
    u32 u = __float_as_uint(f);
    return (u16)((u + 0x7fffu + ((u >> 16) & 1u)) >> 16);
}
__device__ __forceinline__ float lo16(u32 u) { return __uint_as_float(u << 16); }
__device__ __forceinline__ float hi16(u32 u) { return __uint_as_float(u & 0xffff0000u); }
__device__ __forceinline__ u32 pk(float a, float b) {
    return (u32)f2bf(a) | ((u32)f2bf(b) << 16);
}

// AGPR pinning (validated R6-R8)
__device__ __forceinline__ au4 apin(uint4 v) {
    au4 t; t.x = v.x; t.y = v.y; t.z = v.z; t.w = v.w;
    au4 r;
    asm volatile("" : "=a"(r) : "0"(t));
    return r;
}
__device__ __forceinline__ au4 ageta(au4 a) {
    au4 t;
    asm volatile("" : "=a"(t) : "0"(a));
    return t;
}

template <bool IS32>
__device__ __forceinline__ float ldf(const void* p, int i) {
    return IS32 ? ((const float*)p)[i] : bf2f(((const u16*)p)[i]);
}
template <bool IS32>
__device__ __forceinline__ u16 ldbf(const void* p, int i) {
    return IS32 ? f2bf(((const float*)p)[i]) : ((const u16*)p)[i];
}

__device__ __forceinline__ float rcpf(float x) { return __builtin_amdgcn_rcpf(x); }
__device__ __forceinline__ float lipswish(float x) {
    return 0.909f * x * rcpf(1.0f + __expf(-x));   // inf-safe
}
__device__ __forceinline__ float tanh_fast(float x) {
    float e = __expf(2.0f * fabsf(x));
    float t = 1.0f - 2.0f * rcpf(e + 1.0f);
    return copysignf(t, x);
}
__device__ __forceinline__ void split_bf(float v, u16& hi, u16& lo) {
    hi = f2bf(v);
    lo = f2bf(v - bf2f(hi));
}

// R14 = R9 (best: 12 phases, bank-conflict-free layout, single-acc chains,
// per-step stores) + ONE change: dW chunked prefetch.
//   Per-step cold-HBM dW loads (~900cy, m126) were drained by the compiler's
//   vmcnt(0)-before-barrier inside PA2 EVERY step. Now 8 steps of dW (1KB)
//   are fetched into an LDS double buffer (dwraw) once per 8 steps; per-step
//   staging is a trivial LDS->LDS copy. Amortizes the drain 8x.
//   Refuted by R3/R13: MFMA chain-latency edits (both directions) regress.
struct __align__(16) SMem {
    // activations as MFMA B operands: bf16 hi + lo residual
    __align__(16) u16 bxh[BB][96],  bxl[BB][96];        // x=[t,y,pad]
    __align__(16) u16 bh1[2][4][144];                   // [mlp][prt*2+smp][j]
    __align__(16) u16 bh2v[4][144];                     // [prt*2+smp][j]
    __align__(16) u16 bh2c[4][144];                     // [prt*2+smp][j]
    __align__(16) u16 vW2F[4][4][64][8];                // drift L2, frag-major
    // raw MFMA outputs, 4 columns (0,1 = samples hi; 2,3 = samples lo)
    __align__(16) float accL2v[4][72];
    __align__(16) float accL0[4][264];
    __align__(16) float accB[4][1032];                  // also hosts L1 raw acc
    __align__(16) float b0s[256], b1s[256], vb2[HDIM], vsc[HDIM];
    __align__(16) float cb2[HN], csc[HN];
    __align__(16) float roW[8][HDIM];
    __align__(16) float rob[8];
    __align__(16) float tsb[1028];
    __align__(16) float yb[BB][HDIM], g0b[BB][HDIM], fdt[BB][HDIM];
    __align__(16) float dwb[BB][NZ];
    __align__(16) uint4 dwraw[2][8][8];                 // dW chunk dbuf (R14)
};

__device__ __forceinline__ bf16x8 bfrag(const u16* p) {
    return __builtin_bit_cast(bf16x8, *(const uint4*)p);
}
__device__ __forceinline__ fx4 mf1(au4 a, bf16x8 b, fx4 acc) {
    bf16x8 af = __builtin_bit_cast(bf16x8, ageta(a));
    return __builtin_amdgcn_mfma_f32_16x16x32_bf16(af, b, acc, 0, 0, 0);
}

template <bool IS32>
__device__ __forceinline__ uint4 load8(const void* src, int row, int stride, int k0, int Klim) {
    u16 e[8];
    #pragma unroll
    for (int j = 0; j < 8; ++j) {
        int k = k0 + j;
        e[j] = (k < Klim) ? ldbf<IS32>(src, row * stride + k) : (u16)0;
    }
    uint4 v;
    v.x = (u32)e[0] | ((u32)e[1] << 16);
    v.y = (u32)e[2] | ((u32)e[3] << 16);
    v.z = (u32)e[4] | ((u32)e[5] << 16);
    v.w = (u32)e[6] | ((u32)e[7] << 16);
    return v;
}

template <bool IS32>
__device__ __forceinline__ void stage_dw(SMem& sm, const uint4& d, int q, float sdt) {
    if (IS32) {
        const float* pf = (const float*)&d;
        int f = q * 4;
        #pragma unroll
        for (int k = 0; k < 4; ++k)
            sm.dwb[(f + k) >> 4][(f + k) & 15] = pf[k] * sdt;
    } else {
        int f = q * 8;
        u32 u0 = d.x, u1 = d.y, u2 = d.z, u3 = d.w;
        sm.dwb[(f    ) >> 4][(f    ) & 15] = lo16(u0) * sdt;
        sm.dwb[(f + 1) >> 4][(f + 1) & 15] = hi16(u0) * sdt;
        sm.dwb[(f + 2) >> 4][(f + 2) & 15] = lo16(u1) * sdt;
        sm.dwb[(f + 3) >> 4][(f + 3) & 15] = hi16(u1) * sdt;
        sm.dwb[(f + 4) >> 4][(f + 4) & 15] = lo16(u2) * sdt;
        sm.dwb[(f + 5) >> 4][(f + 5) & 15] = hi16(u2) * sdt;
        sm.dwb[(f + 6) >> 4][(f + 6) & 15] = lo16(u3) * sdt;
        sm.dwb[(f + 7) >> 4][(f + 7) & 15] = hi16(u3) * sdt;
    }
}

template <bool IS32>
__device__ __forceinline__ void write_out(void* out, size_t idx, const float* v8) {
    if (IS32) {
        float4 o0, o1;
        o0.x = v8[0]; o0.y = v8[1]; o0.z = v8[2]; o0.w = v8[3];
        o1.x = v8[4]; o1.y = v8[5]; o1.z = v8[6]; o1.w = v8[7];
        ((float4*)out)[idx * 2]     = o0;
        ((float4*)out)[idx * 2 + 1] = o1;
    } else {
        uint4 o;
        o.x = pk(v8[0], v8[1]);
        o.y = pk(v8[2], v8[3]);
        o.z = pk(v8[4], v8[5]);
        o.w = pk(v8[6], v8[7]);
        ((uint4*)out)[idx] = o;
    }
}

template <bool IS32>
__device__ __forceinline__ void
sde_run(SMem& sm,
        const void* ts,  const void* z0,  const void* dW,
        const void* iW0, const void* ib0, const void* iW1, const void* ib1,
        const void* iW2, const void* ib2,
        const void* vW0, const void* vb0, const void* vW1, const void* vb1,
        const void* vW2, const void* vb2, const void* vsc,
        const void* cW0, const void* cb0, const void* cW1, const void* cb1,
        const void* cW2, const void* cb2, const void* csc,
        const void* roW, const void* rob, void* out,
        int tid, int bid)
{
    const int lane = tid & 63, wv = tid >> 6;
    const int mm = lane & 15, qq = lane >> 4;
    const int nn = mm;                 // B/D column within tile
    const int smp = nn & 1;            // sample this column carries
    const int prt = (nn >> 1) & 1;     // 0 = hi part, 1 = lo part

    // ---- weight A-fragments -> AGPRs (184 u32/thread) ----
    au4 a0[6];    // stacked [vW0;cW0]: rows 16(2wv+rtl)+mm, kt 0..2 (K=65 pad 96)
    au4 a1[8];    // waves0-3 vW1, waves4-7 cW1: rows 16(2(wv&3)+rtl)+mm, kt 0..3
    au4 ab[32];   // cW2: rows 128wv+16r8+mm, kt 0..3
    #pragma unroll
    for (int rtl = 0; rtl < 2; ++rtl) {
        int grow = 16 * (2 * wv + rtl) + mm;
        const void* src = (grow < 128) ? vW0 : cW0;
        int r = grow & 127;
        #pragma unroll
        for (int kt = 0; kt < 3; ++kt)
            a0[rtl * 3 + kt] = apin(load8<IS32>(src, r, IND, 32 * kt + 8 * qq, IND));
    }
    {
        const void* src = (wv < 4) ? vW1 : cW1;
        int wl = wv & 3;
        #pragma unroll
        for (int rtl = 0; rtl < 2; ++rtl) {
            int r = 16 * (2 * wl + rtl) + mm;
            #pragma unroll
            for (int kt = 0; kt < 4; ++kt)
                a1[rtl * 4 + kt] = apin(load8<IS32>(src, r, WID, 32 * kt + 8 * qq, WID));
        }
    }
    #pragma unroll
    for (int r8 = 0; r8 < 8; ++r8) {
        int r = 128 * wv + 16 * r8 + mm;
        #pragma unroll
        for (int kt = 0; kt < 4; ++kt)
            ab[r8 * 4 + kt] = apin(load8<IS32>(cW2, r, WID, 32 * kt + 8 * qq, WID));
    }

    // ---- LDS staging ----
    for (int slot = tid; slot < 1024; slot += NTHREADS) {
        int rt = slot >> 8, kt = (slot >> 6) & 3, l = slot & 63;
        int m = l & 15, q = l >> 4;
        uint4 v = load8<IS32>(vW2, 16 * rt + m, WID, 32 * kt + 8 * q, WID);
        *(uint4*)&sm.vW2F[rt][kt][l][0] = v;
    }
    if (tid < 256) {
        sm.b0s[tid] = (tid < 128) ? ldf<IS32>(vb0, tid) : ldf<IS32>(cb0, tid - 128);
        sm.b1s[tid] = (tid < 128) ? ldf<IS32>(vb1, tid) : ldf<IS32>(cb1, tid - 128);
    } else if (tid < 320) {
        int i = tid - 256;
        sm.vb2[i] = ldf<IS32>(vb2, i);
        sm.vsc[i] = ldf<IS32>(vsc, i);
    } else if (tid < 328) {
        sm.rob[tid - 320] = ldf<IS32>(rob, tid - 320);
    } else if (tid >= 384 && tid < 448) {
        int b = (tid - 384) >> 5, k = 65 + ((tid - 384) & 31);
        if (k < 96) { sm.bxh[b][k] = 0; sm.bxl[b][k] = 0; }
    }
    for (int i = tid; i < HN; i += NTHREADS) {
        sm.cb2[i] = ldf<IS32>(cb2, i);
        sm.csc[i] = ldf<IS32>(csc, i);
    }
    { int d = tid >> 6, i2 = tid & 63; sm.roW[d][i2] = ldf<IS32>(roW, tid); }
    for (int i = tid; i < TPTS; i += NTHREADS) sm.tsb[i] = ldf<IS32>(ts, i);

    // dW chunk 0 (steps 0..7) -> dwraw[0]  (R14)
    if (tid >= 128 && tid < 192) {
        int idx = tid - 128;
        if (IS32) {
            int k = idx >> 3, q = idx & 7;
            sm.dwraw[0][k][q] = ((const uint4*)dW)[(size_t)k * 2048 + bid * 8 + q];
        } else if (idx < 32) {
            int k = idx >> 2, q = idx & 3;
            sm.dwraw[0][k][q] = ((const uint4*)dW)[(size_t)k * 1024 + bid * 4 + q];
        }
    }
    __syncthreads();

    const float dt  = sm.tsb[1] - sm.tsb[0];
    const float sdt = sqrtf(dt);
    if (tid >= 128 && tid < 136) {
        int q = tid - 128;
        if (IS32 || q < 4) {
            uint4 d = sm.dwraw[0][0][q];
            stage_dw<IS32>(sm, d, q, sdt);
        }
    }

    // ---- initial MLP (VALU, once): z0 -> 128 -> 128 -> y0; scratch accB[0..1] ----
    if (tid < 256) {
        int b = tid >> 7, j = tid & 127;
        float acc = ldf<IS32>(ib0, j);
        #pragma unroll
        for (int k = 0; k < 8; ++k)
            acc = fmaf(ldf<IS32>(iW0, j * 8 + k), ldf<IS32>(z0, (bid * BB + b) * 8 + k), acc);
        sm.accB[0][b * 128 + j] = fmaxf(acc, 0.0f);
    }
    __syncthreads();
    if (tid < 256) {
        int b = tid >> 7, j = tid & 127;
        float acc = ldf<IS32>(ib1, j);
        for (int k = 0; k < WID; ++k)
            acc = fmaf(ldf<IS32>(iW1, j * WID + k), sm.accB[0][b * 128 + k], acc);
        sm.accB[1][b * 128 + j] = fmaxf(acc, 0.0f);
    }
    __syncthreads();
    if (tid < 128) {
        int b = tid >> 6, i = tid & 63;
        float y0 = ldf<IS32>(ib2, i);
        for (int k = 0; k < WID; ++k)
            y0 = fmaf(ldf<IS32>(iW2, i * WID + k), sm.accB[1][b * 128 + k], y0);
        sm.yb[b][i] = y0;
        u16 hi, lo; split_bf(y0, hi, lo);
        sm.bxh[b][1 + i] = hi; sm.bxl[b][1 + i] = lo;
        if (i == 0) {
            u16 thi, tlo; split_bf(sm.tsb[0], thi, tlo);
            sm.bxh[b][0] = thi; sm.bxl[b][0] = tlo;
        }
    }
    __syncthreads();

    // ---- main scan: 12 barriers/step (R9 structure) ----
    for (int s = 0; s < STEPS; ++s) {
        // PA: L0 both MLPs on x (all waves) -> raw accL0 cols 0-3; stage dwb (s>0)
        if (s > 0 && tid >= 128 && tid < 136) {
            int q = tid - 128;
            if (IS32 || q < 4) {
                uint4 d = sm.dwraw[(s >> 3) & 1][s & 7][q];
                stage_dw<IS32>(sm, d, q, sdt);
            }
        }
        {
            const u16* xs = prt ? &sm.bxl[smp][0] : &sm.bxh[smp][0];
            bf16x8 bx[3];
            #pragma unroll
            for (int kt = 0; kt < 3; ++kt) bx[kt] = bfrag(&xs[32 * kt + 8 * qq]);
            #pragma unroll
            for (int rtl = 0; rtl < 2; ++rtl) {
                fx4 acc = {0.f, 0.f, 0.f, 0.f};
                #pragma unroll
                for (int kt = 0; kt < 3; ++kt) acc = mf1(a0[rtl * 3 + kt], bx[kt], acc);
                int rowb = 16 * (2 * wv + rtl) + 4 * qq;
                if (nn < 4) *(fx4*)&sm.accL0[nn][rowb] = acc;
            }
        }
        __syncthreads();
        // PB: act L0 (512 thr): fold hi+lo cols -> bh1
        {
            int r = tid >> 1, c = tid & 1;
            float h = lipswish(sm.accL0[c][r] + sm.accL0[c + 2][r] + sm.b0s[r]);
            u16 hi, lo; split_bf(h, hi, lo);
            int mlp = r >> 7, j = r & 127;
            sm.bh1[mlp][c][j]     = hi;
            sm.bh1[mlp][2 + c][j] = lo;
        }
        __syncthreads();
        // PC: L1 MFMA (waves0-3 drift, 4-7 diffusion) -> raw acc (accB scratch)
        {
            int mlp = (wv < 4) ? 0 : 1, wl = wv & 3;
            const u16* hs = &sm.bh1[mlp][prt * 2 + smp][0];
            bf16x8 bf[4];
            #pragma unroll
            for (int kt = 0; kt < 4; ++kt) bf[kt] = bfrag(&hs[32 * kt + 8 * qq]);
            #pragma unroll
            for (int rtl = 0; rtl < 2; ++rtl) {
                fx4 acc = {0.f, 0.f, 0.f, 0.f};
                #pragma unroll
                for (int kt = 0; kt < 4; ++kt) acc = mf1(a1[rtl * 4 + kt], bf[kt], acc);
                int rowb = mlp * 128 + 16 * (2 * wl + rtl) + 4 * qq;
                if (nn < 4) *(fx4*)&sm.accB[nn][rowb] = acc;
            }
        }
        __syncthreads();
        // PD: act L1 (512 thr) -> bh2v / bh2c
        {
            int r = tid >> 1, c = tid & 1;
            float h = lipswish(sm.accB[c][r] + sm.accB[c + 2][r] + sm.b1s[r]);
            u16 hi, lo; split_bf(h, hi, lo);
            if (r < 128) { sm.bh2v[c][r]           = hi; sm.bh2v[2 + c][r]           = lo; }
            else         { sm.bh2c[c][r - 128]     = hi; sm.bh2c[2 + c][r - 128]     = lo; }
        }
        __syncthreads();
        // PE: big MFMA eval1 (all waves) -> accB; drift L2 (waves 0-3) -> accL2v
        {
            const u16* cs2 = &sm.bh2c[prt * 2 + smp][0];
            bf16x8 bc[4];
            #pragma unroll
            for (int kt = 0; kt < 4; ++kt) bc[kt] = bfrag(&cs2[32 * kt + 8 * qq]);
            #pragma unroll
            for (int r8 = 0; r8 < 8; ++r8) {
                fx4 acc = {0.f, 0.f, 0.f, 0.f};
                #pragma unroll
                for (int kt = 0; kt < 4; ++kt) acc = mf1(ab[r8 * 4 + kt], bc[kt], acc);
                int rowb = 128 * wv + 16 * r8 + 4 * qq;
                if (nn < 4) *(fx4*)&sm.accB[nn][rowb] = acc;
            }
            if (wv < 4) {
                const u16* vs2 = &sm.bh2v[prt * 2 + smp][0];
                fx4 acc = {0.f, 0.f, 0.f, 0.f};
                #pragma unroll
                for (int kt = 0; kt < 4; ++kt) {
                    bf16x8 aw = bfrag(&sm.vW2F[wv][kt][lane][0]);
                    acc = __builtin_amdgcn_mfma_f32_16x16x32_bf16(aw, bfrag(&vs2[32 * kt + 8 * qq]), acc, 0, 0, 0);
                }
                int i0 = 16 * wv + 4 * qq;
                if (nn < 4) *(fx4*)&sm.accL2v[nn][i0] = acc;
            }
        }
        __syncthreads();
        // PF: epilogue 1 (512 thr): g0 fold; fdt (tid<128); x' pack
        {
            int b = tid >> 8, h = (tid >> 2) & 63, q4 = tid & 3;
            int rb = 16 * h + 4 * q4;
            fx4 aH = *(const fx4*)&sm.accB[b][rb];
            fx4 aL = *(const fx4*)&sm.accB[b + 2][rb];
            float4 cb = *(const float4*)&sm.cb2[rb];
            float4 cs = *(const float4*)&sm.csc[rb];
            float4 dw = *(const float4*)&sm.dwb[b][4 * q4];
            float v;
            v  = tanh_fast(aH.x + aL.x + cb.x) * cs.x * dw.x;
            v  = fmaf(tanh_fast(aH.y + aL.y + cb.y) * cs.y, dw.y, v);
            v  = fmaf(tanh_fast(aH.z + aL.z + cb.z) * cs.z, dw.z, v);
            v  = fmaf(tanh_fast(aH.w + aL.w + cb.w) * cs.w, dw.w, v);
            v += __shfl_xor(v, 1);
            v += __shfl_xor(v, 2);
            if (tid < 128) {
                int b2 = tid >> 6, i = tid & 63;
                sm.fdt[b2][i] = sm.vsc[i] * tanh_fast(sm.accL2v[b2][i] + sm.accL2v[b2 + 2][i] + sm.vb2[i]) * dt;
            }
            if (q4 == 0) {
                sm.g0b[b][h] = v;
                float xp = sm.yb[b][h] + v;
                u16 hi, lo; split_bf(xp, hi, lo);
                sm.bxh[b][1 + h] = hi; sm.bxl[b][1 + h] = lo;
            }
        }
        __syncthreads();
        // PA2: diffusion L0 on x' (waves 4-7) | readout y_s (tid<128)
        //      | dW chunk prefetch (once per 8 steps)
        if (wv >= 4) {
            const u16* xs = prt ? &sm.bxl[smp][0] : &sm.bxh[smp][0];
            bf16x8 bx[3];
            #pragma unroll
            for (int kt = 0; kt < 3; ++kt) bx[kt] = bfrag(&xs[32 * kt + 8 * qq]);
            #pragma unroll
            for (int rtl = 0; rtl < 2; ++rtl) {
                fx4 acc = {0.f, 0.f, 0.f, 0.f};
                #pragma unroll
                for (int kt = 0; kt < 3; ++kt) acc = mf1(a0[rtl * 3 + kt], bx[kt], acc);
                int rowb = 16 * (2 * wv + rtl) + 4 * qq;   // 128..255
                if (nn < 4) *(fx4*)&sm.accL0[nn][rowb] = acc;
            }
        } else if (tid < 128) {
            int b = tid >> 6, i = tid & 63;
            float y = sm.yb[b][i];
            float acc8[8];
            #pragma unroll
            for (int d = 0; d < 8; ++d) acc8[d] = sm.roW[d][i] * y;
            #pragma unroll
            for (int m = 1; m < 64; m <<= 1) {
                #pragma unroll
                for (int d = 0; d < 8; ++d) acc8[d] += __shfl_xor(acc8[d], m);
            }
            if (i == 0) {
                float v8[8];
                #pragma unroll
                for (int d = 0; d < 8; ++d) v8[d] = acc8[d] + sm.rob[d];
                write_out<IS32>(out, (size_t)(bid * BB + b) * TPTS + s, v8);
            }
        } else if (tid >= 128 && tid < 192 && (s & 7) == 0 && s + 8 < STEPS) {
            int idx = tid - 128;
            int buf = ((s >> 3) + 1) & 1;
            if (IS32) {
                int k = idx >> 3, q = idx & 7;
                sm.dwraw[buf][k][q] = ((const uint4*)dW)[(size_t)(s + 8 + k) * 2048 + bid * 8 + q];
            } else if (idx < 32) {
                int k = idx >> 2, q = idx & 3;
                sm.dwraw[buf][k][q] = ((const uint4*)dW)[(size_t)(s + 8 + k) * 1024 + bid * 4 + q];
            }
        }
        __syncthreads();
        // PB2: act diffusion L0 (256 thr)
        if (tid < 256) {
            int r = 128 + (tid >> 1), c = tid & 1;
            float h = lipswish(sm.accL0[c][r] + sm.accL0[c + 2][r] + sm.b0s[r]);
            u16 hi, lo; split_bf(h, hi, lo);
            sm.bh1[1][c][r - 128]     = hi;
            sm.bh1[1][2 + c][r - 128] = lo;
        }
        __syncthreads();
        // PC2: diffusion L1 MFMA (waves 4-7) -> accB scratch
        if (wv >= 4) {
            int wl = wv & 3;
            const u16* hs = &sm.bh1[1][prt * 2 + smp][0];
            bf16x8 bf[4];
            #pragma unroll
            for (int kt = 0; kt < 4; ++kt) bf[kt] = bfrag(&hs[32 * kt + 8 * qq]);
            #pragma unroll
            for (int rtl = 0; rtl < 2; ++rtl) {
                fx4 acc = {0.f, 0.f, 0.f, 0.f};
                #pragma unroll
                for (int kt = 0; kt < 4; ++kt) acc = mf1(a1[rtl * 4 + kt], bf[kt], acc);
                int rowb = 128 + 16 * (2 * wl + rtl) + 4 * qq;
                if (nn < 4) *(fx4*)&sm.accB[nn][rowb] = acc;
            }
        }
        __syncthreads();
        // PD2: act diffusion L1 (256 thr)
        if (tid < 256) {
            int r = 128 + (tid >> 1), c = tid & 1;
            float h = lipswish(sm.accB[c][r] + sm.accB[c + 2][r] + sm.b1s[r]);
            u16 hi, lo; split_bf(h, hi, lo);
            sm.bh2c[c][r - 128]     = hi;
            sm.bh2c[2 + c][r - 128] = lo;
        }
        __syncthreads();
        // PE2: big MFMA eval2 (all waves) -> accB
        {
            const u16* cs2 = &sm.bh2c[prt * 2 + smp][0];
            bf16x8 bc[4];
            #pragma unroll
            for (int kt = 0; kt < 4; ++kt) bc[kt] = bfrag(&cs2[32 * kt + 8 * qq]);
            #pragma unroll
            for (int r8 = 0; r8 < 8; ++r8) {
                fx4 acc = {0.f, 0.f, 0.f, 0.f};
                #pragma unroll
                for (int kt = 0; kt < 4; ++kt) acc = mf1(ab[r8 * 4 + kt], bc[kt], acc);
                int rowb = 128 * wv + 16 * r8 + 4 * qq;
                if (nn < 4) *(fx4*)&sm.accB[nn][rowb] = acc;
            }
        }
        __syncthreads();
        // PF2: epilogue 2 (512 thr): g1 fold; y1 update + next-x pack + t
        {
            int b = tid >> 8, h = (tid >> 2) & 63, q4 = tid & 3;
            int rb = 16 * h + 4 * q4;
            fx4 aH = *(const fx4*)&sm.accB[b][rb];
            fx4 aL = *(const fx4*)&sm.accB[b + 2][rb];
            float4 cb = *(const float4*)&sm.cb2[rb];
            float4 cs = *(const float4*)&sm.csc[rb];
            float4 dw = *(const float4*)&sm.dwb[b][4 * q4];
            float v;
            v  = tanh_fast(aH.x + aL.x + cb.x) * cs.x * dw.x;
            v  = fmaf(tanh_fast(aH.y + aL.y + cb.y) * cs.y, dw.y, v);
            v  = fmaf(tanh_fast(aH.z + aL.z + cb.z) * cs.z, dw.z, v);
            v  = fmaf(tanh_fast(aH.w + aL.w + cb.w) * cs.w, dw.w, v);
            v += __shfl_xor(v, 1);
            v += __shfl_xor(v, 2);
            if (q4 == 0) {
                float y1 = sm.yb[b][h] + sm.fdt[b][h] + 0.5f * (sm.g0b[b][h] + v);
                sm.yb[b][h] = y1;
                u16 hi, lo; split_bf(y1, hi, lo);
                sm.bxh[b][1 + h] = hi; sm.bxl[b][1 + h] = lo;
                if (h == 0) {
                    u16 thi, tlo; split_bf(sm.tsb[s + 1], thi, tlo);
                    sm.bxh[b][0] = thi; sm.bxl[b][0] = tlo;
                }
            }
        }
        __syncthreads();
    }

    // final readout: y_1024
    if (tid < 128) {
        int b = tid >> 6, i = tid & 63;
        float y = sm.yb[b][i];
        float acc8[8];
        #pragma unroll
        for (int d = 0; d < 8; ++d) acc8[d] = sm.roW[d][i] * y;
        #pragma unroll
        for (int m = 1; m < 64; m <<= 1) {
            #pragma unroll
            for (int d = 0; d < 8; ++d) acc8[d] += __shfl_xor(acc8[d], m);
        }
        if (i == 0) {
            float v8[8];
            #pragma unroll
            for (int d = 0; d < 8; ++d) v8[d] = acc8[d] + sm.rob[d];
            write_out<IS32>(out, (size_t)(bid * BB + b) * TPTS + STEPS, v8);
        }
    }
}

__global__ void
__attribute__((amdgpu_flat_work_group_size(NTHREADS, NTHREADS), amdgpu_waves_per_eu(2, 2)))
sde_kernel(const void* __restrict__ ts,  const void* __restrict__ z0,  const void* __restrict__ dW,
           const void* __restrict__ iW0, const void* __restrict__ ib0, const void* __restrict__ iW1,
           const void* __restrict__ ib1, const void* __restrict__ iW2, const void* __restrict__ ib2,
           const void* __restrict__ vW0, const void* __restrict__ vb0, const void* __restrict__ vW1,
           const void* __restrict__ vb1, const void* __restrict__ vW2, const void* __restrict__ vb2,
           const void* __restrict__ vsc, const void* __restrict__ cW0, const void* __restrict__ cb0,
           const void* __restrict__ cW1, const void* __restrict__ cb1, const void* __restrict__ cW2,
           const void* __restrict__ cb2, const void* __restrict__ csc, const void* __restrict__ roW,
           const void* __restrict__ rob, void* __restrict__ out)
{
    __shared__ SMem sm;
    const int tid = threadIdx.x;
    const int bid = blockIdx.x;

    // dtype detection: u16 word #1 of ts (bf16 -> 0x3A80 != 0; fp32 -> 0)
    const bool is32 = (((const u16*)ts)[1] == 0);

    if (is32) {
        sde_run<true>(sm, ts, z0, dW, iW0, ib0, iW1, ib1, iW2, ib2,
                      vW0, vb0, vW1, vb1, vW2, vb2, vsc,
                      cW0, cb0, cW1, cb1, cW2, cb2, csc, roW, rob, out, tid, bid);
    } else {
        sde_run<false>(sm, ts, z0, dW, iW0, ib0, iW1, ib1, iW2, ib2,
                       vW0, vb0, vW1, vb1, vW2, vb2, vsc,
                       cW0, cb0, cW1, cb1, cW2, cb2, csc, roW, rob, out, tid, bid);
    }
}

extern "C" void kernel_launch(void* const* d_in, const int* in_sizes, int n_in,
                              void* d_out, int out_size, void* d_ws, size_t ws_size,
                              hipStream_t stream) {
    (void)in_sizes; (void)n_in; (void)d_ws; (void)ws_size; (void)out_size;
    hipLaunchKernelGGL(sde_kernel, dim3(NBLOCKS), dim3(NTHREADS), 0, stream,
                       d_in[0], d_in[1], d_in[2], d_in[3], d_in[4], d_in[5], d_in[6],
                       d_in[7], d_in[8], d_in[9], d_in[10], d_in[11], d_in[12], d_in[13],
                       d_in[14], d_in[15], d_in[16], d_in[17], d_in[18], d_in[19], d_in[20],
                       d_in[21], d_in[22], d_in[23], d_in[24], d_out);
}

// Round 8
// 4978.522 us; speedup vs baseline: 2.2958x; 1.0961x over previous
//
#include <hip/hip_runtime.h>

typedef unsigned short u16;
typedef unsigned int   u32;
typedef __attribute__((ext_vector_type(4))) unsigned int au4;
typedef __attribute__((ext_vector_type(4))) float fx4;
typedef __attribute__((ext_vector_type(8))) __bf16 bf16x8;

#define NTHREADS 512
#define NBLOCKS  256
#define BB       2
#define STEPS    1024
#define TPTS     1025
#define HDIM     64
#define NZ       16
#define WID      128
#define IND      65
#define HN       1024

__device__ __forceinline__ float bf2f(u16 v) { return __uint_as_float(((u32)v) << 16); }
__device__ __forceinline__ u16 f2bf(float f) {
    u32 u = __float_as_uint(f);
    return (u16)((u + 0x7fffu + ((u >> 16) & 1u)) >> 16);
}
__device__ __forceinline__ float lo16(u32 u) { return __uint_as_float(u << 16); }
__device__ __forceinline__ float hi16(u32 u) { return __uint_as_float(u & 0xffff0000u); }

// AGPR pinning (validated R6-R8)
__device__ __forceinline__ au4 apin(uint4 v) {
    au4 t; t.x = v.x; t.y = v.y; t.z = v.z; t.w = v.w;
    au4 r;
    asm volatile("" : "=a"(r) : "0"(t));
    return r;
}
__device__ __forceinline__ au4 ageta(au4 a) {
    au4 t;
    asm volatile("" : "=a"(t) : "0"(a));
    return t;
}

template <bool IS32>
__device__ __forceinline__ float ldf(const void* p, int i) {
    return IS32 ? ((const float*)p)[i] : bf2f(((const u16*)p)[i]);
}
template <bool IS32>
__device__ __forceinline__ u16 ldbf(const void* p, int i) {
    return IS32 ? f2bf(((const float*)p)[i]) : ((const u16*)p)[i];
}

__device__ __forceinline__ float rcpf(float x) { return __builtin_amdgcn_rcpf(x); }
__device__ __forceinline__ float lipswish(float x) {
    return 0.909f * x * rcpf(1.0f + __expf(-x));   // inf-safe
}
__device__ __forceinline__ float tanh_fast(float x) {
    float e = __expf(2.0f * fabsf(x));
    float t = 1.0f - 2.0f * rcpf(e + 1.0f);
    return copysignf(t, x);
}
__device__ __forceinline__ void split_bf(float v, u16& hi, u16& lo) {
    hi = f2bf(v);
    lo = f2bf(v - bf2f(hi));
}

// R15 = R14 (best) + two phase-rebalance micro-opts:
//  1. readout: 48-shfl butterfly (incl. LDS-unit xor8/16/32 swizzles) replaced
//     by transposed-roW dot (roWT[i][d], bank-verified 2-way max) + 3 DPP-fast
//     shfl_xor(1,2,4) + 8-lane scalar stores. ~400cy -> ~150cy on PA2's
//     critical path.
//  2. drift-fdt tanh moved from PF into PC2, where waves 0-3 were idle.
//  Everything else byte-identical to R14 (12 phases, dW chunk dbuf,
//  bank-conflict-free layout). Refuted by R2/R3/R13: barrier merges and
//  chain reshaping regress; R4: >2 waves/SIMD spills weight state.
struct __align__(16) SMem {
    // activations as MFMA B operands: bf16 hi + lo residual
    __align__(16) u16 bxh[BB][96],  bxl[BB][96];        // x=[t,y,pad]
    __align__(16) u16 bh1[2][4][144];                   // [mlp][prt*2+smp][j]
    __align__(16) u16 bh2v[4][144];                     // [prt*2+smp][j]
    __align__(16) u16 bh2c[4][144];                     // [prt*2+smp][j]
    __align__(16) u16 vW2F[4][4][64][8];                // drift L2, frag-major
    // raw MFMA outputs, 4 columns (0,1 = samples hi; 2,3 = samples lo)
    __align__(16) float accL2v[4][72];
    __align__(16) float accL0[4][264];
    __align__(16) float accB[4][1032];                  // also hosts L1 raw acc
    __align__(16) float b0s[256], b1s[256], vb2[HDIM], vsc[HDIM];
    __align__(16) float cb2[HN], csc[HN];
    __align__(16) float roWT[HDIM][8];                  // transposed readout W (R15)
    __align__(16) float rob[8];
    __align__(16) float tsb[1028];
    __align__(16) float yb[BB][HDIM], g0b[BB][HDIM], fdt[BB][HDIM];
    __align__(16) float dwb[BB][NZ];
    __align__(16) uint4 dwraw[2][8][8];                 // dW chunk dbuf (R14)
};

__device__ __forceinline__ bf16x8 bfrag(const u16* p) {
    return __builtin_bit_cast(bf16x8, *(const uint4*)p);
}
__device__ __forceinline__ fx4 mf1(au4 a, bf16x8 b, fx4 acc) {
    bf16x8 af = __builtin_bit_cast(bf16x8, ageta(a));
    return __builtin_amdgcn_mfma_f32_16x16x32_bf16(af, b, acc, 0, 0, 0);
}

template <bool IS32>
__device__ __forceinline__ uint4 load8(const void* src, int row, int stride, int k0, int Klim) {
    u16 e[8];
    #pragma unroll
    for (int j = 0; j < 8; ++j) {
        int k = k0 + j;
        e[j] = (k < Klim) ? ldbf<IS32>(src, row * stride + k) : (u16)0;
    }
    uint4 v;
    v.x = (u32)e[0] | ((u32)e[1] << 16);
    v.y = (u32)e[2] | ((u32)e[3] << 16);
    v.z = (u32)e[4] | ((u32)e[5] << 16);
    v.w = (u32)e[6] | ((u32)e[7] << 16);
    return v;
}

template <bool IS32>
__device__ __forceinline__ void stage_dw(SMem& sm, const uint4& d, int q, float sdt) {
    if (IS32) {
        const float* pf = (const float*)&d;
        int f = q * 4;
        #pragma unroll
        for (int k = 0; k < 4; ++k)
            sm.dwb[(f + k) >> 4][(f + k) & 15] = pf[k] * sdt;
    } else {
        int f = q * 8;
        u32 u0 = d.x, u1 = d.y, u2 = d.z, u3 = d.w;
        sm.dwb[(f    ) >> 4][(f    ) & 15] = lo16(u0) * sdt;
        sm.dwb[(f + 1) >> 4][(f + 1) & 15] = hi16(u0) * sdt;
        sm.dwb[(f + 2) >> 4][(f + 2) & 15] = lo16(u1) * sdt;
        sm.dwb[(f + 3) >> 4][(f + 3) & 15] = hi16(u1) * sdt;
        sm.dwb[(f + 4) >> 4][(f + 4) & 15] = lo16(u2) * sdt;
        sm.dwb[(f + 5) >> 4][(f + 5) & 15] = hi16(u2) * sdt;
        sm.dwb[(f + 6) >> 4][(f + 6) & 15] = lo16(u3) * sdt;
        sm.dwb[(f + 7) >> 4][(f + 7) & 15] = hi16(u3) * sdt;
    }
}

// R15 readout: lane l of the b-wave handles dim d = l>>3, octet k8 = l&7.
// 8-term FMA over i = k8+8t (roWT 2-way banks, yb broadcast), 3 DPP shfl,
// k8==0 lanes store one scalar each (8 stores span one 16/32B line).
template <bool IS32>
__device__ __forceinline__ void readout(const SMem& sm, void* out, int bid, int b,
                                        int l, size_t t)
{
    int d = l >> 3, k8 = l & 7;
    float acc = 0.f;
    #pragma unroll
    for (int t8 = 0; t8 < 8; ++t8) {
        int i = k8 + 8 * t8;
        acc = fmaf(sm.roWT[i][d], sm.yb[b][i], acc);
    }
    acc += __shfl_xor(acc, 1);
    acc += __shfl_xor(acc, 2);
    acc += __shfl_xor(acc, 4);
    if (k8 == 0) {
        float val = acc + sm.rob[d];
        size_t idx = (size_t)(bid * BB + b) * TPTS + t;
        if (IS32) ((float*)out)[idx * 8 + d] = val;
        else      ((u16*)out)[idx * 8 + d] = f2bf(val);
    }
}

template <bool IS32>
__device__ __forceinline__ void
sde_run(SMem& sm,
        const void* ts,  const void* z0,  const void* dW,
        const void* iW0, const void* ib0, const void* iW1, const void* ib1,
        const void* iW2, const void* ib2,
        const void* vW0, const void* vb0, const void* vW1, const void* vb1,
        const void* vW2, const void* vb2, const void* vsc,
        const void* cW0, const void* cb0, const void* cW1, const void* cb1,
        const void* cW2, const void* cb2, const void* csc,
        const void* roW, const void* rob, void* out,
        int tid, int bid)
{
    const int lane = tid & 63, wv = tid >> 6;
    const int mm = lane & 15, qq = lane >> 4;
    const int nn = mm;                 // B/D column within tile
    const int smp = nn & 1;            // sample this column carries
    const int prt = (nn >> 1) & 1;     // 0 = hi part, 1 = lo part

    // ---- weight A-fragments -> AGPRs (184 u32/thread) ----
    au4 a0[6];    // stacked [vW0;cW0]: rows 16(2wv+rtl)+mm, kt 0..2 (K=65 pad 96)
    au4 a1[8];    // waves0-3 vW1, waves4-7 cW1: rows 16(2(wv&3)+rtl)+mm, kt 0..3
    au4 ab[32];   // cW2: rows 128wv+16r8+mm, kt 0..3
    #pragma unroll
    for (int rtl = 0; rtl < 2; ++rtl) {
        int grow = 16 * (2 * wv + rtl) + mm;
        const void* src = (grow < 128) ? vW0 : cW0;
        int r = grow & 127;
        #pragma unroll
        for (int kt = 0; kt < 3; ++kt)
            a0[rtl * 3 + kt] = apin(load8<IS32>(src, r, IND, 32 * kt + 8 * qq, IND));
    }
    {
        const void* src = (wv < 4) ? vW1 : cW1;
        int wl = wv & 3;
        #pragma unroll
        for (int rtl = 0; rtl < 2; ++rtl) {
            int r = 16 * (2 * wl + rtl) + mm;
            #pragma unroll
            for (int kt = 0; kt < 4; ++kt)
                a1[rtl * 4 + kt] = apin(load8<IS32>(src, r, WID, 32 * kt + 8 * qq, WID));
        }
    }
    #pragma unroll
    for (int r8 = 0; r8 < 8; ++r8) {
        int r = 128 * wv + 16 * r8 + mm;
        #pragma unroll
        for (int kt = 0; kt < 4; ++kt)
            ab[r8 * 4 + kt] = apin(load8<IS32>(cW2, r, WID, 32 * kt + 8 * qq, WID));
    }

    // ---- LDS staging ----
    for (int slot = tid; slot < 1024; slot += NTHREADS) {
        int rt = slot >> 8, kt = (slot >> 6) & 3, l = slot & 63;
        int m = l & 15, q = l >> 4;
        uint4 v = load8<IS32>(vW2, 16 * rt + m, WID, 32 * kt + 8 * q, WID);
        *(uint4*)&sm.vW2F[rt][kt][l][0] = v;
    }
    if (tid < 256) {
        sm.b0s[tid] = (tid < 128) ? ldf<IS32>(vb0, tid) : ldf<IS32>(cb0, tid - 128);
        sm.b1s[tid] = (tid < 128) ? ldf<IS32>(vb1, tid) : ldf<IS32>(cb1, tid - 128);
    } else if (tid < 320) {
        int i = tid - 256;
        sm.vb2[i] = ldf<IS32>(vb2, i);
        sm.vsc[i] = ldf<IS32>(vsc, i);
    } else if (tid < 328) {
        sm.rob[tid - 320] = ldf<IS32>(rob, tid - 320);
    } else if (tid >= 384 && tid < 448) {
        int b = (tid - 384) >> 5, k = 65 + ((tid - 384) & 31);
        if (k < 96) { sm.bxh[b][k] = 0; sm.bxl[b][k] = 0; }
    }
    for (int i = tid; i < HN; i += NTHREADS) {
        sm.cb2[i] = ldf<IS32>(cb2, i);
        sm.csc[i] = ldf<IS32>(csc, i);
    }
    { int d = tid >> 6, i2 = tid & 63; sm.roWT[i2][d] = ldf<IS32>(roW, tid); }
    for (int i = tid; i < TPTS; i += NTHREADS) sm.tsb[i] = ldf<IS32>(ts, i);

    // dW chunk 0 (steps 0..7) -> dwraw[0]  (R14)
    if (tid >= 128 && tid < 192) {
        int idx = tid - 128;
        if (IS32) {
            int k = idx >> 3, q = idx & 7;
            sm.dwraw[0][k][q] = ((const uint4*)dW)[(size_t)k * 2048 + bid * 8 + q];
        } else if (idx < 32) {
            int k = idx >> 2, q = idx & 3;
            sm.dwraw[0][k][q] = ((const uint4*)dW)[(size_t)k * 1024 + bid * 4 + q];
        }
    }
    __syncthreads();

    const float dt  = sm.tsb[1] - sm.tsb[0];
    const float sdt = sqrtf(dt);
    if (tid >= 128 && tid < 136) {
        int q = tid - 128;
        if (IS32 || q < 4) {
            uint4 d = sm.dwraw[0][0][q];
            stage_dw<IS32>(sm, d, q, sdt);
        }
    }

    // ---- initial MLP (VALU, once): z0 -> 128 -> 128 -> y0; scratch accB[0..1] ----
    if (tid < 256) {
        int b = tid >> 7, j = tid & 127;
        float acc = ldf<IS32>(ib0, j);
        #pragma unroll
        for (int k = 0; k < 8; ++k)
            acc = fmaf(ldf<IS32>(iW0, j * 8 + k), ldf<IS32>(z0, (bid * BB + b) * 8 + k), acc);
        sm.accB[0][b * 128 + j] = fmaxf(acc, 0.0f);
    }
    __syncthreads();
    if (tid < 256) {
        int b = tid >> 7, j = tid & 127;
        float acc = ldf<IS32>(ib1, j);
        for (int k = 0; k < WID; ++k)
            acc = fmaf(ldf<IS32>(iW1, j * WID + k), sm.accB[0][b * 128 + k], acc);
        sm.accB[1][b * 128 + j] = fmaxf(acc, 0.0f);
    }
    __syncthreads();
    if (tid < 128) {
        int b = tid >> 6, i = tid & 63;
        float y0 = ldf<IS32>(ib2, i);
        for (int k = 0; k < WID; ++k)
            y0 = fmaf(ldf<IS32>(iW2, i * WID + k), sm.accB[1][b * 128 + k], y0);
        sm.yb[b][i] = y0;
        u16 hi, lo; split_bf(y0, hi, lo);
        sm.bxh[b][1 + i] = hi; sm.bxl[b][1 + i] = lo;
        if (i == 0) {
            u16 thi, tlo; split_bf(sm.tsb[0], thi, tlo);
            sm.bxh[b][0] = thi; sm.bxl[b][0] = tlo;
        }
    }
    __syncthreads();

    // ---- main scan: 12 barriers/step (R9 structure) ----
    for (int s = 0; s < STEPS; ++s) {
        // PA: L0 both MLPs on x (all waves) -> raw accL0 cols 0-3; stage dwb (s>0)
        if (s > 0 && tid >= 128 && tid < 136) {
            int q = tid - 128;
            if (IS32 || q < 4) {
                uint4 d = sm.dwraw[(s >> 3) & 1][s & 7][q];
                stage_dw<IS32>(sm, d, q, sdt);
            }
        }
        {
            const u16* xs = prt ? &sm.bxl[smp][0] : &sm.bxh[smp][0];
            bf16x8 bx[3];
            #pragma unroll
            for (int kt = 0; kt < 3; ++kt) bx[kt] = bfrag(&xs[32 * kt + 8 * qq]);
            #pragma unroll
            for (int rtl = 0; rtl < 2; ++rtl) {
                fx4 acc = {0.f, 0.f, 0.f, 0.f};
                #pragma unroll
                for (int kt = 0; kt < 3; ++kt) acc = mf1(a0[rtl * 3 + kt], bx[kt], acc);
                int rowb = 16 * (2 * wv + rtl) + 4 * qq;
                if (nn < 4) *(fx4*)&sm.accL0[nn][rowb] = acc;
            }
        }
        __syncthreads();
        // PB: act L0 (512 thr): fold hi+lo cols -> bh1
        {
            int r = tid >> 1, c = tid & 1;
            float h = lipswish(sm.accL0[c][r] + sm.accL0[c + 2][r] + sm.b0s[r]);
            u16 hi, lo; split_bf(h, hi, lo);
            int mlp = r >> 7, j = r & 127;
            sm.bh1[mlp][c][j]     = hi;
            sm.bh1[mlp][2 + c][j] = lo;
        }
        __syncthreads();
        // PC: L1 MFMA (waves0-3 drift, 4-7 diffusion) -> raw acc (accB scratch)
        {
            int mlp = (wv < 4) ? 0 : 1, wl = wv & 3;
            const u16* hs = &sm.bh1[mlp][prt * 2 + smp][0];
            bf16x8 bf[4];
            #pragma unroll
            for (int kt = 0; kt < 4; ++kt) bf[kt] = bfrag(&hs[32 * kt + 8 * qq]);
            #pragma unroll
            for (int rtl = 0; rtl < 2; ++rtl) {
                fx4 acc = {0.f, 0.f, 0.f, 0.f};
                #pragma unroll
                for (int kt = 0; kt < 4; ++kt) acc = mf1(a1[rtl * 4 + kt], bf[kt], acc);
                int rowb = mlp * 128 + 16 * (2 * wl + rtl) + 4 * qq;
                if (nn < 4) *(fx4*)&sm.accB[nn][rowb] = acc;
            }
        }
        __syncthreads();
        // PD: act L1 (512 thr) -> bh2v / bh2c
        {
            int r = tid >> 1, c = tid & 1;
            float h = lipswish(sm.accB[c][r] + sm.accB[c + 2][r] + sm.b1s[r]);
            u16 hi, lo; split_bf(h, hi, lo);
            if (r < 128) { sm.bh2v[c][r]           = hi; sm.bh2v[2 + c][r]           = lo; }
            else         { sm.bh2c[c][r - 128]     = hi; sm.bh2c[2 + c][r - 128]     = lo; }
        }
        __syncthreads();
        // PE: big MFMA eval1 (all waves) -> accB; drift L2 (waves 0-3) -> accL2v
        {
            const u16* cs2 = &sm.bh2c[prt * 2 + smp][0];
            bf16x8 bc[4];
            #pragma unroll
            for (int kt = 0; kt < 4; ++kt) bc[kt] = bfrag(&cs2[32 * kt + 8 * qq]);
            #pragma unroll
            for (int r8 = 0; r8 < 8; ++r8) {
                fx4 acc = {0.f, 0.f, 0.f, 0.f};
                #pragma unroll
                for (int kt = 0; kt < 4; ++kt) acc = mf1(ab[r8 * 4 + kt], bc[kt], acc);
                int rowb = 128 * wv + 16 * r8 + 4 * qq;
                if (nn < 4) *(fx4*)&sm.accB[nn][rowb] = acc;
            }
            if (wv < 4) {
                const u16* vs2 = &sm.bh2v[prt * 2 + smp][0];
                fx4 acc = {0.f, 0.f, 0.f, 0.f};
                #pragma unroll
                for (int kt = 0; kt < 4; ++kt) {
                    bf16x8 aw = bfrag(&sm.vW2F[wv][kt][lane][0]);
                    acc = __builtin_amdgcn_mfma_f32_16x16x32_bf16(aw, bfrag(&vs2[32 * kt + 8 * qq]), acc, 0, 0, 0);
                }
                int i0 = 16 * wv + 4 * qq;
                if (nn < 4) *(fx4*)&sm.accL2v[nn][i0] = acc;
            }
        }
        __syncthreads();
        // PF: epilogue 1 (512 thr): g0 fold; x' pack  (fdt moved to PC2, R15)
        {
            int b = tid >> 8, h = (tid >> 2) & 63, q4 = tid & 3;
            int rb = 16 * h + 4 * q4;
            fx4 aH = *(const fx4*)&sm.accB[b][rb];
            fx4 aL = *(const fx4*)&sm.accB[b + 2][rb];
            float4 cb = *(const float4*)&sm.cb2[rb];
            float4 cs = *(const float4*)&sm.csc[rb];
            float4 dw = *(const float4*)&sm.dwb[b][4 * q4];
            float v;
            v  = tanh_fast(aH.x + aL.x + cb.x) * cs.x * dw.x;
            v  = fmaf(tanh_fast(aH.y + aL.y + cb.y) * cs.y, dw.y, v);
            v  = fmaf(tanh_fast(aH.z + aL.z + cb.z) * cs.z, dw.z, v);
            v  = fmaf(tanh_fast(aH.w + aL.w + cb.w) * cs.w, dw.w, v);
            v += __shfl_xor(v, 1);
            v += __shfl_xor(v, 2);
            if (q4 == 0) {
                sm.g0b[b][h] = v;
                float xp = sm.yb[b][h] + v;
                u16 hi, lo; split_bf(xp, hi, lo);
                sm.bxh[b][1 + h] = hi; sm.bxl[b][1 + h] = lo;
            }
        }
        __syncthreads();
        // PA2: diffusion L0 on x' (waves 4-7) | readout y_s (tid<128, R15 fast)
        //      | dW chunk prefetch (once per 8 steps)
        if (wv >= 4) {
            const u16* xs = prt ? &sm.bxl[smp][0] : &sm.bxh[smp][0];
            bf16x8 bx[3];
            #pragma unroll
            for (int kt = 0; kt < 3; ++kt) bx[kt] = bfrag(&xs[32 * kt + 8 * qq]);
            #pragma unroll
            for (int rtl = 0; rtl < 2; ++rtl) {
                fx4 acc = {0.f, 0.f, 0.f, 0.f};
                #pragma unroll
                for (int kt = 0; kt < 3; ++kt) acc = mf1(a0[rtl * 3 + kt], bx[kt], acc);
                int rowb = 16 * (2 * wv + rtl) + 4 * qq;   // 128..255
                if (nn < 4) *(fx4*)&sm.accL0[nn][rowb] = acc;
            }
        } else if (tid < 128) {
            readout<IS32>(sm, out, bid, tid >> 6, tid & 63, (size_t)s);
        } else if (tid >= 128 && tid < 192 && (s & 7) == 0 && s + 8 < STEPS) {
            int idx = tid - 128;
            int buf = ((s >> 3) + 1) & 1;
            if (IS32) {
                int k = idx >> 3, q = idx & 7;
                sm.dwraw[buf][k][q] = ((const uint4*)dW)[(size_t)(s + 8 + k) * 2048 + bid * 8 + q];
            } else if (idx < 32) {
                int k = idx >> 2, q = idx & 3;
                sm.dwraw[buf][k][q] = ((const uint4*)dW)[(size_t)(s + 8 + k) * 1024 + bid * 4 + q];
            }
        }
        __syncthreads();
        // PB2: act diffusion L0 (256 thr)
        if (tid < 256) {
            int r = 128 + (tid >> 1), c = tid & 1;
            float h = lipswish(sm.accL0[c][r] + sm.accL0[c + 2][r] + sm.b0s[r]);
            u16 hi, lo; split_bf(h, hi, lo);
            sm.bh1[1][c][r - 128]     = hi;
            sm.bh1[1][2 + c][r - 128] = lo;
        }
        __syncthreads();
        // PC2: diffusion L1 MFMA (waves 4-7) -> accB scratch | fdt (tid<128, R15)
        if (wv >= 4) {
            int wl = wv & 3;
            const u16* hs = &sm.bh1[1][prt * 2 + smp][0];
            bf16x8 bf[4];
            #pragma unroll
            for (int kt = 0; kt < 4; ++kt) bf[kt] = bfrag(&hs[32 * kt + 8 * qq]);
            #pragma unroll
            for (int rtl = 0; rtl < 2; ++rtl) {
                fx4 acc = {0.f, 0.f, 0.f, 0.f};
                #pragma unroll
                for (int kt = 0; kt < 4; ++kt) acc = mf1(a1[rtl * 4 + kt], bf[kt], acc);
                int rowb = 128 + 16 * (2 * wl + rtl) + 4 * qq;
                if (nn < 4) *(fx4*)&sm.accB[nn][rowb] = acc;
            }
        } else if (tid < 128) {
            int b2 = tid >> 6, i = tid & 63;
            sm.fdt[b2][i] = sm.vsc[i] * tanh_fast(sm.accL2v[b2][i] + sm.accL2v[b2 + 2][i] + sm.vb2[i]) * dt;
        }
        __syncthreads();
        // PD2: act diffusion L1 (256 thr)
        if (tid < 256) {
            int r = 128 + (tid >> 1), c = tid & 1;
            float h = lipswish(sm.accB[c][r] + sm.accB[c + 2][r] + sm.b1s[r]);
            u16 hi, lo; split_bf(h, hi, lo);
            sm.bh2c[c][r - 128]     = hi;
            sm.bh2c[2 + c][r - 128] = lo;
        }
        __syncthreads();
        // PE2: big MFMA eval2 (all waves) -> accB
        {
            const u16* cs2 = &sm.bh2c[prt * 2 + smp][0];
            bf16x8 bc[4];
            #pragma unroll
            for (int kt = 0; kt < 4; ++kt) bc[kt] = bfrag(&cs2[32 * kt + 8 * qq]);
            #pragma unroll
            for (int r8 = 0; r8 < 8; ++r8) {
                fx4 acc = {0.f, 0.f, 0.f, 0.f};
                #pragma unroll
                for (int kt = 0; kt < 4; ++kt) acc = mf1(ab[r8 * 4 + kt], bc[kt], acc);
                int rowb = 128 * wv + 16 * r8 + 4 * qq;
                if (nn < 4) *(fx4*)&sm.accB[nn][rowb] = acc;
            }
        }
        __syncthreads();
        // PF2: epilogue 2 (512 thr): g1 fold; y1 update + next-x pack + t
        {
            int b = tid >> 8, h = (tid >> 2) & 63, q4 = tid & 3;
            int rb = 16 * h + 4 * q4;
            fx4 aH = *(const fx4*)&sm.accB[b][rb];
            fx4 aL = *(const fx4*)&sm.accB[b + 2][rb];
            float4 cb = *(const float4*)&sm.cb2[rb];
            float4 cs = *(const float4*)&sm.csc[rb];
            float4 dw = *(const float4*)&sm.dwb[b][4 * q4];
            float v;
            v  = tanh_fast(aH.x + aL.x + cb.x) * cs.x * dw.x;
            v  = fmaf(tanh_fast(aH.y + aL.y + cb.y) * cs.y, dw.y, v);
            v  = fmaf(tanh_fast(aH.z + aL.z + cb.z) * cs.z, dw.z, v);
            v  = fmaf(tanh_fast(aH.w + aL.w + cb.w) * cs.w, dw.w, v);
            v += __shfl_xor(v, 1);
            v += __shfl_xor(v, 2);
            if (q4 == 0) {
                float y1 = sm.yb[b][h] + sm.fdt[b][h] + 0.5f * (sm.g0b[b][h] + v);
                sm.yb[b][h] = y1;
                u16 hi, lo; split_bf(y1, hi, lo);
                sm.bxh[b][1 + h] = hi; sm.bxl[b][1 + h] = lo;
                if (h == 0) {
                    u16 thi, tlo; split_bf(sm.tsb[s + 1], thi, tlo);
                    sm.bxh[b][0] = thi; sm.bxl[b][0] = tlo;
                }
            }
        }
        __syncthreads();
    }

    // final readout: y_1024
    if (tid < 128) {
        readout<IS32>(sm, out, bid, tid >> 6, tid & 63, (size_t)STEPS);
    }
}

__global__ void
__attribute__((amdgpu_flat_work_group_size(NTHREADS, NTHREADS), amdgpu_waves_per_eu(2, 2)))
sde_kernel(const void* __restrict__ ts,  const void* __restrict__ z0,  const void* __restrict__ dW,
           const void* __restrict__ iW0, const void* __restrict__ ib0, const void* __restrict__ iW1,
           const void* __restrict__ ib1, const void* __restrict__ iW2, const void* __restrict__ ib2,
           const void* __restrict__ vW0, const void* __restrict__ vb0, const void* __restrict__ vW1,
           const void* __restrict__ vb1, const void* __restrict__ vW2, const void* __restrict__ vb2,
           const void* __restrict__ vsc, const void* __restrict__ cW0, const void* __restrict__ cb0,
           const void* __restrict__ cW1, const void* __restrict__ cb1, const void* __restrict__ cW2,
           const void* __restrict__ cb2, const void* __restrict__ csc, const void* __restrict__ roW,
           const void* __restrict__ rob, void* __restrict__ out)
{
    __shared__ SMem sm;
    const int tid = threadIdx.x;
    const int bid = blockIdx.x;

    // dtype detection: u16 word #1 of ts (bf16 -> 0x3A80 != 0; fp32 -> 0)
    const bool is32 = (((const u16*)ts)[1] == 0);

    if (is32) {
        sde_run<true>(sm, ts, z0, dW, iW0, ib0, iW1, ib1, iW2, ib2,
                      vW0, vb0, vW1, vb1, vW2, vb2, vsc,
                      cW0, cb0, cW1, cb1, cW2, cb2, csc, roW, rob, out, tid, bid);
    } else {
        sde_run<false>(sm, ts, z0, dW, iW0, ib0, iW1, ib1, iW2, ib2,
                       vW0, vb0, vW1, vb1, vW2, vb2, vsc,
                       cW0, cb0, cW1, cb1, cW2, cb2, csc, roW, rob, out, tid, bid);
    }
}

extern "C" void kernel_launch(void* const* d_in, const int* in_sizes, int n_in,
                              void* d_out, int out_size, void* d_ws, size_t ws_size,
                              hipStream_t stream) {
    (void)in_sizes; (void)n_in; (void)d_ws; (void)ws_size; (void)out_size;
    hipLaunchKernelGGL(sde_kernel, dim3(NBLOCKS), dim3(NTHREADS), 0, stream,
                       d_in[0], d_in[1], d_in[2], d_in[3], d_in[4], d_in[5], d_in[6],
                       d_in[7], d_in[8], d_in[9], d_in[10], d_in[11], d_in[12], d_in[13],
                       d_in[14], d_in[15], d_in[16], d_in[17], d_in[18], d_in[19], d_in[20],
                       d_in[21], d_in[22], d_in[23], d_in[24], d_out);
}